// Round 2
// baseline (3235.626 us; speedup 1.0000x reference)
//
#include <hip/hip_runtime.h>
#include <hip/hip_fp16.h>

#define TN 64
#define BN 2048
#define G 4
#define NBLK (BN / G)   // 512 blocks x 512 threads, 2 blocks/CU

__device__ __forceinline__ float fast_sigmoid(float x) {
    // rcp(1+exp(-x)); x->-inf: exp=inf -> rcp=0 ✓; x->+inf: -> 1 ✓; no NaN
    return __builtin_amdgcn_rcpf(1.f + __expf(-x));
}
__device__ __forceinline__ float fast_tanh(float x) {
    return fmaf(2.f, fast_sigmoid(2.f * x), -1.f);
}

// ---- precompute: HW[b,t,f] = H[b,t,:] @ W1[256:384,:] + b1, stored fp16 with
// ---- 16B-chunk XOR swizzle (chunk c of row (b,t) stored at c ^ (t&15)).
__global__ __launch_bounds__(256) void precompute_hw(
    const float* __restrict__ H, const float* __restrict__ W1,
    const float* __restrict__ b1, __half* __restrict__ HWh) {
    __shared__ float sH[16 * 128];
    const int i = threadIdx.x;
    const long r0 = (long)blockIdx.x * 16;
    #pragma unroll
    for (int u = 0; u < 8; ++u) sH[u * 256 + i] = H[r0 * 128 + u * 256 + i];
    __syncthreads();
    const int f = i & 127;
    const int half_ = i >> 7;
    float acc[8];
    float bb = b1[f];
    #pragma unroll
    for (int u = 0; u < 8; ++u) acc[u] = bb;
    #pragma unroll 4
    for (int h = 0; h < 128; ++h) {
        float wv = W1[(256 + h) * 128 + f];
        #pragma unroll
        for (int u = 0; u < 8; ++u)
            acc[u] = fmaf(sH[(half_ + 2 * u) * 128 + h], wv, acc[u]);
    }
    const int c = f >> 3, fi = f & 7;
    #pragma unroll
    for (int u = 0; u < 8; ++u) {
        long r = r0 + half_ + 2 * u;
        int t = (int)(r & 63);
        int cs = c ^ (t & 15);
        HWh[r * 128 + cs * 8 + fi] = __float2half(acc[u]);
    }
}

// ---- pack W1[0:256][128] into j-quad float4s: W1p[j4*128+f] = W1[j4*4+c][f]
__global__ __launch_bounds__(256) void pack_w1(
    const float* __restrict__ W1, float4* __restrict__ W1p) {
    int tid = blockIdx.x * 256 + threadIdx.x;   // 8192
    int j4 = tid >> 7, f = tid & 127;
    W1p[tid] = make_float4(W1[(j4 * 4 + 0) * 128 + f], W1[(j4 * 4 + 1) * 128 + f],
                           W1[(j4 * 4 + 2) * 128 + f], W1[(j4 * 4 + 3) * 128 + f]);
}

// ---- pack Whh^T into k-quad float4s: WTp[k4*512+n] = Whh[n][k4*4+c]
__global__ __launch_bounds__(256) void pack_wt(
    const float* __restrict__ Whh, float4* __restrict__ WTp) {
    int tid = blockIdx.x * 256 + threadIdx.x;   // 16384
    int k4 = tid >> 9, n = tid & 511;
    WTp[k4 * 512 + n] = *(const float4*)&Whh[n * 128 + k4 * 4];
}

// ---- persistent scan: block owns G=4 batch elems, 512 threads, HW tile in LDS
__global__ __launch_bounds__(512, 4) void decoder_scan(
    const float* __restrict__ H, const float* __restrict__ Y,
    const float* __restrict__ W2, const float* __restrict__ Wih,
    const float* __restrict__ bih, const float* __restrict__ bhh,
    const float* __restrict__ fcW, const float* __restrict__ fcb,
    const float* __restrict__ fcfW, const float* __restrict__ fcfb,
    const __half* __restrict__ HWh, const float4* __restrict__ W1p,
    const float4* __restrict__ WTp, float* __restrict__ out) {

    __shared__ __align__(16) __half sHW[4 * 64 * 128];  // 65536 B, swizzled
    __shared__ __align__(16) float sdc[4 * 256];        // [d|c] fp32, 4096 B
    __shared__ __align__(16) float sp[4 * 128];         // p, then ctx  2048 B
    __shared__ __align__(16) float sbeta[4 * 64];       // 1024 B
    __shared__ __align__(16) float scratch[2048];       // 8192 B shared scratch
    __shared__ __align__(16) float sW2[128];            // 512 B
    __shared__ float sy[4];

    const int tid = threadIdx.x;
    const int bbase = blockIdx.x * G;
    const int g_hi = tid >> 7;    // (g,f) / (jc,f) decomposition
    const int f_lo = tid & 127;
    const int lane = tid & 63;
    const int wv = tid >> 6;

    // ---- init: copy swizzled HW tile (64 KB), zero state, preload regs ----
    {
        const uint4* src = (const uint4*)(HWh + (long)bbase * (TN * 128));
        uint4* dst = (uint4*)sHW;
        #pragma unroll
        for (int u = 0; u < 8; ++u) dst[u * 512 + tid] = src[u * 512 + tid];
    }
    sdc[tid] = 0.f; sdc[tid + 512] = 0.f;
    if (tid < 128) sW2[tid] = W2[tid];
    const float wih_r = Wih[tid];
    const float bsum_r = bih[tid] + bhh[tid];
    const float fcw0 = fcW[lane], fcw1 = fcW[lane + 64];
    const float fcw2 = fcW[128], fcb0 = fcb[0];
    __syncthreads();

    #pragma unroll 1
    for (int t = 0; t < TN; ++t) {
        // ---- ph1p: partial p = dc @ W1_dc over j-chunk jc=g_hi ----
        {
            const int jc = g_hi, f = f_lo;
            float a0 = 0.f, a1 = 0.f, a2 = 0.f, a3 = 0.f;
            #pragma unroll
            for (int u = 0; u < 16; ++u) {
                float4 w = W1p[(jc * 16 + u) * 128 + f];
                float4 d0 = *(const float4*)&sdc[0 * 256 + jc * 64 + u * 4];
                float4 d1 = *(const float4*)&sdc[1 * 256 + jc * 64 + u * 4];
                float4 d2 = *(const float4*)&sdc[2 * 256 + jc * 64 + u * 4];
                float4 d3 = *(const float4*)&sdc[3 * 256 + jc * 64 + u * 4];
                a0 = fmaf(d0.x, w.x, fmaf(d0.y, w.y, fmaf(d0.z, w.z, fmaf(d0.w, w.w, a0))));
                a1 = fmaf(d1.x, w.x, fmaf(d1.y, w.y, fmaf(d1.z, w.z, fmaf(d1.w, w.w, a1))));
                a2 = fmaf(d2.x, w.x, fmaf(d2.y, w.y, fmaf(d2.z, w.z, fmaf(d2.w, w.w, a2))));
                a3 = fmaf(d3.x, w.x, fmaf(d3.y, w.y, fmaf(d3.z, w.z, fmaf(d3.w, w.w, a3))));
            }
            scratch[0 * 512 + jc * 128 + f_lo] = a0;
            scratch[1 * 512 + jc * 128 + f_lo] = a1;
            scratch[2 * 512 + jc * 128 + f_lo] = a2;
            scratch[3 * 512 + jc * 128 + f_lo] = a3;
        }
        __syncthreads();
        // ---- ph1red: p[g][f] ----
        sp[tid] = scratch[g_hi * 512 + f_lo] + scratch[g_hi * 512 + 128 + f_lo]
                + scratch[g_hi * 512 + 256 + f_lo] + scratch[g_hi * 512 + 384 + f_lo];
        __syncthreads();

        // ---- ph2: e[g][t'] = sum_f tanh(HW+p)*W2, thread=(g,fc,t') ----
        {
            const int g = tid >> 7, fc = (tid >> 6) & 1, tt = tid & 63;
            const int rowc = (g * 64 + tt) * 16;   // chunk units
            const int sw = tt & 15;
            float e_acc = 0.f;
            #pragma unroll
            for (int u = 0; u < 8; ++u) {
                int c = fc * 8 + u;
                uint4 hv = *(const uint4*)&sHW[(rowc + (c ^ sw)) * 8];
                const __half2* hp = (const __half2*)&hv;
                float4 pv0 = *(const float4*)&sp[g * 128 + c * 8];
                float4 pv1 = *(const float4*)&sp[g * 128 + c * 8 + 4];
                float4 w0 = *(const float4*)&sW2[c * 8];
                float4 w1 = *(const float4*)&sW2[c * 8 + 4];
                float2 h0 = __half22float2(hp[0]);
                float2 h1 = __half22float2(hp[1]);
                float2 h2 = __half22float2(hp[2]);
                float2 h3 = __half22float2(hp[3]);
                e_acc = fmaf(fast_tanh(h0.x + pv0.x), w0.x, e_acc);
                e_acc = fmaf(fast_tanh(h0.y + pv0.y), w0.y, e_acc);
                e_acc = fmaf(fast_tanh(h1.x + pv0.z), w0.z, e_acc);
                e_acc = fmaf(fast_tanh(h1.y + pv0.w), w0.w, e_acc);
                e_acc = fmaf(fast_tanh(h2.x + pv1.x), w1.x, e_acc);
                e_acc = fmaf(fast_tanh(h2.y + pv1.y), w1.y, e_acc);
                e_acc = fmaf(fast_tanh(h3.x + pv1.z), w1.z, e_acc);
                e_acc = fmaf(fast_tanh(h3.y + pv1.w), w1.w, e_acc);
            }
            scratch[(g * 2 + fc) * 64 + tt] = e_acc;
        }
        __syncthreads();

        // ---- ph3: softmax over T (waves 0-3, wave g) ----
        if (wv < 4) {
            float e = scratch[wv * 128 + lane] + scratch[wv * 128 + 64 + lane];
            float m = e;
            #pragma unroll
            for (int d = 1; d < 64; d <<= 1) m = fmaxf(m, __shfl_xor(m, d, 64));
            float ex = __expf(e - m);
            float s = ex;
            #pragma unroll
            for (int d = 1; d < 64; d <<= 1) s += __shfl_xor(s, d, 64);
            sbeta[wv * 64 + lane] = ex * __builtin_amdgcn_rcpf(s);
        }
        __syncthreads();

        // ---- ph4p: context partials, thread=(g,tc,fo), float4 H reads ----
        {
            const int g = tid >> 7, tc = (tid >> 5) & 3, fo = tid & 31;
            const float* hb = H + ((long)(bbase + g) * TN) * 128 + fo * 4;
            float a0 = 0.f, a1 = 0.f, a2 = 0.f, a3 = 0.f;
            #pragma unroll
            for (int k = 0; k < 16; ++k) {
                int tt = tc * 16 + k;
                float4 hv = *(const float4*)(hb + tt * 128);
                float bw = sbeta[g * 64 + tt];
                a0 = fmaf(hv.x, bw, a0);
                a1 = fmaf(hv.y, bw, a1);
                a2 = fmaf(hv.z, bw, a2);
                a3 = fmaf(hv.w, bw, a3);
            }
            *(float4*)&scratch[(g * 4 + tc) * 128 + fo * 4] = make_float4(a0, a1, a2, a3);
        }
        __syncthreads();
        // ---- ph4red: ctx[g][f] (kept in register for epilogue + sp for ph5) ----
        {
            float c = scratch[g_hi * 512 + f_lo] + scratch[g_hi * 512 + 128 + f_lo]
                    + scratch[g_hi * 512 + 256 + f_lo] + scratch[g_hi * 512 + 384 + f_lo];
            sp[tid] = c;
        }
        __syncthreads();

        // ---- ph5: y_tilde (waves 0-3) ----
        if (wv < 4) {
            float part = sp[wv * 128 + lane] * fcw0 + sp[wv * 128 + 64 + lane] * fcw1;
            #pragma unroll
            for (int d = 1; d < 64; d <<= 1) part += __shfl_xor(part, d, 64);
            if (lane == 0) {
                float yv = Y[(bbase + wv) * TN + t];
                sy[wv] = fmaf(yv, fcw2, part + fcb0);
            }
        }
        __syncthreads();

        // ---- ph6: gates[g][n] = y~*Wih + d@WhhT + bsum, thread=n ----
        {
            float a0 = fmaf(sy[0], wih_r, bsum_r);
            float a1 = fmaf(sy[1], wih_r, bsum_r);
            float a2 = fmaf(sy[2], wih_r, bsum_r);
            float a3 = fmaf(sy[3], wih_r, bsum_r);
            #pragma unroll
            for (int k4 = 0; k4 < 32; ++k4) {
                float4 w = WTp[k4 * 512 + tid];
                float4 d0 = *(const float4*)&sdc[0 * 256 + k4 * 4];
                float4 d1 = *(const float4*)&sdc[1 * 256 + k4 * 4];
                float4 d2 = *(const float4*)&sdc[2 * 256 + k4 * 4];
                float4 d3 = *(const float4*)&sdc[3 * 256 + k4 * 4];
                a0 = fmaf(d0.x, w.x, fmaf(d0.y, w.y, fmaf(d0.z, w.z, fmaf(d0.w, w.w, a0))));
                a1 = fmaf(d1.x, w.x, fmaf(d1.y, w.y, fmaf(d1.z, w.z, fmaf(d1.w, w.w, a1))));
                a2 = fmaf(d2.x, w.x, fmaf(d2.y, w.y, fmaf(d2.z, w.z, fmaf(d2.w, w.w, a2))));
                a3 = fmaf(d3.x, w.x, fmaf(d3.y, w.y, fmaf(d3.z, w.z, fmaf(d3.w, w.w, a3))));
            }
            scratch[0 * 512 + tid] = a0;
            scratch[1 * 512 + tid] = a1;
            scratch[2 * 512 + tid] = a2;
            scratch[3 * 512 + tid] = a3;
        }
        __syncthreads();

        // ---- ph7: LSTM cell update, thread=(g,h) ----
        {
            const int g = g_hi, h = f_lo;
            float ig = fast_sigmoid(scratch[g * 512 + h]);
            float fg = fast_sigmoid(scratch[g * 512 + 128 + h]);
            float gt = fast_tanh(scratch[g * 512 + 256 + h]);
            float og = fast_sigmoid(scratch[g * 512 + 384 + h]);
            float cn = fmaf(fg, sdc[g * 256 + 128 + h], ig * gt);
            sdc[g * 256 + h] = og * fast_tanh(cn);
            sdc[g * 256 + 128 + h] = cn;
        }
        __syncthreads();
    }

    // ---- epilogue: y_pred = [d, ctx] @ fcfW + fcfb (waves 0-3) ----
    if (wv < 4) {
        const int g = wv;
        float part = sdc[g * 256 + lane] * fcfW[lane]
                   + sdc[g * 256 + 64 + lane] * fcfW[64 + lane]
                   + sp[g * 128 + lane] * fcfW[128 + lane]
                   + sp[g * 128 + 64 + lane] * fcfW[192 + lane];
        #pragma unroll
        for (int d = 1; d < 64; d <<= 1) part += __shfl_xor(part, d, 64);
        if (lane == 0) out[bbase + g] = part + fcfb[0];
    }
}

extern "C" void kernel_launch(void* const* d_in, const int* in_sizes, int n_in,
                              void* d_out, int out_size, void* d_ws, size_t ws_size,
                              hipStream_t stream) {
    const float* H    = (const float*)d_in[0];
    const float* Y    = (const float*)d_in[1];
    const float* W1   = (const float*)d_in[2];
    const float* b1   = (const float*)d_in[3];
    const float* W2   = (const float*)d_in[4];
    // d_in[5] = attn_b2: softmax-shift-invariant, unused
    const float* Wih  = (const float*)d_in[6];
    const float* Whh  = (const float*)d_in[7];
    const float* bih  = (const float*)d_in[8];
    const float* bhh  = (const float*)d_in[9];
    const float* fcW  = (const float*)d_in[10];
    const float* fcb  = (const float*)d_in[11];
    const float* fcfW = (const float*)d_in[12];
    const float* fcfb = (const float*)d_in[13];

    __half* HWh = (__half*)d_ws;                                   // 33,554,432 B
    float4* W1p = (float4*)((char*)d_ws + 33554432);               // 131,072 B
    float4* WTp = (float4*)((char*)d_ws + 33554432 + 131072);      // 262,144 B
    float* out = (float*)d_out;

    precompute_hw<<<BN * TN / 16, 256, 0, stream>>>(H, W1, b1, HWh);
    pack_w1<<<32, 256, 0, stream>>>(W1, W1p);
    pack_wt<<<64, 256, 0, stream>>>(Whh, WTp);
    decoder_scan<<<NBLK, 512, 0, stream>>>(H, Y, W2, Wih, bih, bhh,
                                           fcW, fcb, fcfW, fcfb,
                                           HWh, W1p, WTp, out);
}

// Round 3
// 2388.025 us; speedup vs baseline: 1.3549x; 1.3549x over previous
//
#include <hip/hip_runtime.h>
#include <hip/hip_fp16.h>

#define TN 64
#define BN 2048
#define G 4
#define NBLK (BN / G)   // 512 blocks x 512 threads, 2 blocks/CU

typedef _Float16 h2f __attribute__((ext_vector_type(2)));
union U4 {
    uint4 u;
    h2f h[4];
    _Float16 f16[8];
};

__device__ __forceinline__ float fast_sigmoid(float x) {
    return __builtin_amdgcn_rcpf(1.f + __expf(-x));
}
__device__ __forceinline__ float fast_tanh(float x) {
    return fmaf(2.f, fast_sigmoid(2.f * x), -1.f);
}

// ---- HW[b,t,f] = H[b,t,:] @ W1[256:384,:] + b1, fp16 linear [b*T+t][128]
__global__ __launch_bounds__(256) void prep_hw(
    const float* __restrict__ H, const float* __restrict__ W1,
    const float* __restrict__ b1, __half* __restrict__ HWh) {
    __shared__ float sH[16 * 128];
    const int i = threadIdx.x;
    const long r0 = (long)blockIdx.x * 16;
    #pragma unroll
    for (int u = 0; u < 8; ++u) sH[u * 256 + i] = H[r0 * 128 + u * 256 + i];
    __syncthreads();
    const int f = i & 127;
    const int half_ = i >> 7;
    float acc[8];
    float bb = b1[f];
    #pragma unroll
    for (int u = 0; u < 8; ++u) acc[u] = bb;
    #pragma unroll 4
    for (int h = 0; h < 128; ++h) {
        float wv = W1[(256 + h) * 128 + f];
        #pragma unroll
        for (int u = 0; u < 8; ++u)
            acc[u] = fmaf(sH[(half_ + 2 * u) * 128 + h], wv, acc[u]);
    }
    #pragma unroll
    for (int u = 0; u < 8; ++u)
        HWh[(r0 + half_ + 2 * u) * 128 + f] = __float2half(acc[u]);
}

// ---- HhT[b][f][t] = fp16(H[b][t][f])  (one block per b)
__global__ __launch_bounds__(256) void prep_ht(
    const float* __restrict__ H, __half* __restrict__ HhT) {
    __shared__ __half sh[64 * 128];
    const int b = blockIdx.x, i = threadIdx.x;
    #pragma unroll
    for (int u = 0; u < 32; ++u) {
        int idx = u * 256 + i;
        sh[idx] = __float2half(H[(long)b * 8192 + idx]);
    }
    __syncthreads();
    const int f = i >> 1, t0 = (i & 1) * 32;
    __half* ob = HhT + (long)b * 8192 + (long)i * 32;
    #pragma unroll
    for (int k = 0; k < 32; ++k) ob[k] = sh[(t0 + k) * 128 + f];
}

// ---- W1q[u][f] = fp16 of W1[u*8+0..7][f] packed as uint4 (u=0..31)
__global__ __launch_bounds__(256) void prep_w1(
    const float* __restrict__ W1, uint4* __restrict__ W1q) {
    int tid = blockIdx.x * 256 + threadIdx.x;   // 4096
    int u = tid >> 7, f = tid & 127;
    __half tmp[8];
    #pragma unroll
    for (int c = 0; c < 8; ++c) tmp[c] = __float2half(W1[(u * 8 + c) * 128 + f]);
    W1q[tid] = *(const uint4*)tmp;
}

// ---- WTq[k8][n] = fp16 of Whh[n][k8*8+0..7] packed as uint4 (k8=0..15)
__global__ __launch_bounds__(256) void prep_wt(
    const float* __restrict__ Whh, uint4* __restrict__ WTq) {
    int tid = blockIdx.x * 256 + threadIdx.x;   // 8192
    int k8 = tid >> 9, n = tid & 511;
    __half tmp[8];
    #pragma unroll
    for (int c = 0; c < 8; ++c) tmp[c] = __float2half(Whh[n * 128 + k8 * 8 + c]);
    WTq[tid] = *(const uint4*)tmp;
}

// ---- persistent scan: G=4 per block, all time-invariant slices in regs/LDS
__global__ __launch_bounds__(512, 4) void decoder_scan(
    const float* __restrict__ Y, const float* __restrict__ W2,
    const float* __restrict__ Wih, const float* __restrict__ bih,
    const float* __restrict__ bhh, const float* __restrict__ fcW,
    const float* __restrict__ fcb, const float* __restrict__ fcfW,
    const float* __restrict__ fcfb,
    const __half* __restrict__ HWh, const __half* __restrict__ HhT,
    const uint4* __restrict__ W1q, const uint4* __restrict__ WTq,
    float* __restrict__ out) {

    __shared__ __align__(16) uint4 sW1[32 * 128];    // 65536 B
    __shared__ __align__(16) __half sdcH[4 * 256];   // 2048 B  [d|c] fp16
    __shared__ __align__(16) float sp[4 * 128];      // 2048 B  p, then ctx
    __shared__ __align__(16) float se[512];          // 2048 B
    __shared__ __align__(16) float sbeta[4 * 64];    // 1024 B
    __shared__ __align__(16) float sg[4 * 512];      // 8192 B  gates
    __shared__ __align__(16) float sW2[128];         // 512 B
    __shared__ float sy[4];                          // total 81424 B

    const int tid = threadIdx.x;
    const int bbase = blockIdx.x * G;
    const int g_hi = tid >> 7;          // ph1/ph4/ph7 mapping (g, f)
    const int f_lo = tid & 127;
    const int lane = tid & 63;
    const int wv = tid >> 6;
    const int g2 = tid >> 7;            // ph2 mapping (g, fc, tt)
    const int fc = (tid >> 6) & 1;
    const int tt = tid & 63;

    // ---- init: LDS W1, register slices, zero state ----
    #pragma unroll
    for (int u = 0; u < 8; ++u) sW1[u * 512 + tid] = W1q[u * 512 + tid];

    uint4 hwr[8];   // HW[g2][tt][fc*64 + 0:64]  fp16
    {
        const uint4* src = (const uint4*)(HWh + (((long)(bbase + g2) * 64 + tt) * 128 + fc * 64));
        #pragma unroll
        for (int u = 0; u < 8; ++u) hwr[u] = src[u];
    }
    uint4 hr[8];    // H[g_hi][0:64][f_lo] fp16 (from HhT)
    {
        const uint4* src = (const uint4*)(HhT + (((long)(bbase + g_hi) * 128 + f_lo) * 64));
        #pragma unroll
        for (int u = 0; u < 8; ++u) hr[u] = src[u];
    }
    sdcH[tid] = __float2half(0.f);
    sdcH[tid + 512] = __float2half(0.f);
    if (tid < 128) sW2[tid] = W2[tid];
    float c_reg = 0.f;                        // cell state, thread (g_hi, f_lo)
    const float wih_r = Wih[tid];
    const float bsum_r = bih[tid] + bhh[tid];
    const float fcw0 = fcW[lane], fcw1 = fcW[lane + 64];
    const float fcw2 = fcW[128], fcb0 = fcb[0];
    __syncthreads();

    #pragma unroll 1
    for (int t = 0; t < TN; ++t) {
        // ---- ph1: p[g][f] = dc_h[g] . W1col_f  (fdot2, W1 from LDS) ----
        {
            const __half* dcb = &sdcH[g_hi * 256];
            float acc = 0.f;
            #pragma unroll
            for (int u = 0; u < 32; ++u) {
                U4 w; w.u = sW1[u * 128 + f_lo];
                U4 d; d.u = *(const uint4*)&dcb[u * 8];
                acc = __builtin_amdgcn_fdot2(d.h[0], w.h[0], acc, false);
                acc = __builtin_amdgcn_fdot2(d.h[1], w.h[1], acc, false);
                acc = __builtin_amdgcn_fdot2(d.h[2], w.h[2], acc, false);
                acc = __builtin_amdgcn_fdot2(d.h[3], w.h[3], acc, false);
            }
            sp[tid] = acc;
        }
        __syncthreads();

        // ---- ph2: partial e over 64 f's, HW from registers ----
        {
            const float* pb = &sp[g2 * 128 + fc * 64];
            const float* w2b = &sW2[fc * 64];
            float eacc = 0.f;
            #pragma unroll
            for (int u = 0; u < 8; ++u) {
                U4 hw; hw.u = hwr[u];
                float4 p0 = *(const float4*)&pb[u * 8];
                float4 p1 = *(const float4*)&pb[u * 8 + 4];
                float4 q0 = *(const float4*)&w2b[u * 8];
                float4 q1 = *(const float4*)&w2b[u * 8 + 4];
                eacc = fmaf(fast_tanh((float)hw.f16[0] + p0.x), q0.x, eacc);
                eacc = fmaf(fast_tanh((float)hw.f16[1] + p0.y), q0.y, eacc);
                eacc = fmaf(fast_tanh((float)hw.f16[2] + p0.z), q0.z, eacc);
                eacc = fmaf(fast_tanh((float)hw.f16[3] + p0.w), q0.w, eacc);
                eacc = fmaf(fast_tanh((float)hw.f16[4] + p1.x), q1.x, eacc);
                eacc = fmaf(fast_tanh((float)hw.f16[5] + p1.y), q1.y, eacc);
                eacc = fmaf(fast_tanh((float)hw.f16[6] + p1.z), q1.z, eacc);
                eacc = fmaf(fast_tanh((float)hw.f16[7] + p1.w), q1.w, eacc);
            }
            se[g2 * 128 + fc * 64 + tt] = eacc;
        }
        __syncthreads();

        // ---- ph3: softmax over T (waves 0-3) ----
        if (wv < 4) {
            float e = se[wv * 128 + lane] + se[wv * 128 + 64 + lane];
            float m = e;
            #pragma unroll
            for (int d = 1; d < 64; d <<= 1) m = fmaxf(m, __shfl_xor(m, d, 64));
            float ex = __expf(e - m);
            float s = ex;
            #pragma unroll
            for (int d = 1; d < 64; d <<= 1) s += __shfl_xor(s, d, 64);
            sbeta[wv * 64 + lane] = ex * __builtin_amdgcn_rcpf(s);
        }
        __syncthreads();

        // ---- ph4: ctx[g][f] = sum_t beta * H  (H from registers) ----
        {
            const float* bb = &sbeta[g_hi * 64];
            float acc = 0.f;
            #pragma unroll
            for (int u = 0; u < 8; ++u) {
                U4 hh; hh.u = hr[u];
                float4 b0 = *(const float4*)&bb[u * 8];
                float4 b1 = *(const float4*)&bb[u * 8 + 4];
                acc = fmaf((float)hh.f16[0], b0.x, acc);
                acc = fmaf((float)hh.f16[1], b0.y, acc);
                acc = fmaf((float)hh.f16[2], b0.z, acc);
                acc = fmaf((float)hh.f16[3], b0.w, acc);
                acc = fmaf((float)hh.f16[4], b1.x, acc);
                acc = fmaf((float)hh.f16[5], b1.y, acc);
                acc = fmaf((float)hh.f16[6], b1.z, acc);
                acc = fmaf((float)hh.f16[7], b1.w, acc);
            }
            sp[tid] = acc;   // overwrite p with ctx (p fully consumed at ph2)
        }
        __syncthreads();

        // ---- ph5: y_tilde[g] (waves 0-3) ----
        if (wv < 4) {
            float part = sp[wv * 128 + lane] * fcw0 + sp[wv * 128 + 64 + lane] * fcw1;
            #pragma unroll
            for (int d = 1; d < 64; d <<= 1) part += __shfl_xor(part, d, 64);
            if (lane == 0) {
                float yv = Y[(bbase + wv) * TN + t];
                sy[wv] = fmaf(yv, fcw2, part + fcb0);
            }
        }
        __syncthreads();

        // ---- ph6: gates[g][n] = y~*Wih + d.WTcol_n + bsum (n = tid) ----
        {
            float a0 = fmaf(sy[0], wih_r, bsum_r);
            float a1 = fmaf(sy[1], wih_r, bsum_r);
            float a2 = fmaf(sy[2], wih_r, bsum_r);
            float a3 = fmaf(sy[3], wih_r, bsum_r);
            const uint4* wcol = WTq + tid;
            #pragma unroll
            for (int k8 = 0; k8 < 16; ++k8) {
                U4 w; w.u = wcol[k8 * 512];
                U4 d0; d0.u = *(const uint4*)&sdcH[0 * 256 + k8 * 8];
                U4 d1; d1.u = *(const uint4*)&sdcH[1 * 256 + k8 * 8];
                U4 d2; d2.u = *(const uint4*)&sdcH[2 * 256 + k8 * 8];
                U4 d3; d3.u = *(const uint4*)&sdcH[3 * 256 + k8 * 8];
                #pragma unroll
                for (int q = 0; q < 4; ++q) {
                    a0 = __builtin_amdgcn_fdot2(d0.h[q], w.h[q], a0, false);
                    a1 = __builtin_amdgcn_fdot2(d1.h[q], w.h[q], a1, false);
                    a2 = __builtin_amdgcn_fdot2(d2.h[q], w.h[q], a2, false);
                    a3 = __builtin_amdgcn_fdot2(d3.h[q], w.h[q], a3, false);
                }
            }
            sg[0 * 512 + tid] = a0;
            sg[1 * 512 + tid] = a1;
            sg[2 * 512 + tid] = a2;
            sg[3 * 512 + tid] = a3;
        }
        __syncthreads();

        // ---- ph7: LSTM cell (c in register), write d,c fp16 ----
        {
            float ig = fast_sigmoid(sg[g_hi * 512 + f_lo]);
            float fg = fast_sigmoid(sg[g_hi * 512 + 128 + f_lo]);
            float gt = fast_tanh(sg[g_hi * 512 + 256 + f_lo]);
            float og = fast_sigmoid(sg[g_hi * 512 + 384 + f_lo]);
            c_reg = fmaf(fg, c_reg, ig * gt);
            float dn = og * fast_tanh(c_reg);
            sdcH[g_hi * 256 + f_lo] = __float2half(dn);
            sdcH[g_hi * 256 + 128 + f_lo] = __float2half(c_reg);
        }
        __syncthreads();
    }

    // ---- epilogue: y_pred = [d, ctx] @ fcfW + fcfb (waves 0-3) ----
    if (wv < 4) {
        const int g = wv;
        float part = __half2float(sdcH[g * 256 + lane]) * fcfW[lane]
                   + __half2float(sdcH[g * 256 + 64 + lane]) * fcfW[64 + lane]
                   + sp[g * 128 + lane] * fcfW[128 + lane]
                   + sp[g * 128 + 64 + lane] * fcfW[192 + lane];
        #pragma unroll
        for (int d = 1; d < 64; d <<= 1) part += __shfl_xor(part, d, 64);
        if (lane == 0) out[bbase + g] = part + fcfb[0];
    }
}

extern "C" void kernel_launch(void* const* d_in, const int* in_sizes, int n_in,
                              void* d_out, int out_size, void* d_ws, size_t ws_size,
                              hipStream_t stream) {
    const float* H    = (const float*)d_in[0];
    const float* Y    = (const float*)d_in[1];
    const float* W1   = (const float*)d_in[2];
    const float* b1   = (const float*)d_in[3];
    const float* W2   = (const float*)d_in[4];
    // d_in[5] = attn_b2: softmax-shift-invariant, unused
    const float* Wih  = (const float*)d_in[6];
    const float* Whh  = (const float*)d_in[7];
    const float* bih  = (const float*)d_in[8];
    const float* bhh  = (const float*)d_in[9];
    const float* fcW  = (const float*)d_in[10];
    const float* fcb  = (const float*)d_in[11];
    const float* fcfW = (const float*)d_in[12];
    const float* fcfb = (const float*)d_in[13];

    char* ws = (char*)d_ws;
    __half* HWh = (__half*)ws;                           // 32 MB
    __half* HhT = (__half*)(ws + (33554432));            // 32 MB
    uint4*  W1q = (uint4*)(ws + 2 * 33554432);           // 64 KB
    uint4*  WTq = (uint4*)(ws + 2 * 33554432 + 65536);   // 128 KB
    float* out = (float*)d_out;

    prep_hw<<<BN * TN / 16, 256, 0, stream>>>(H, W1, b1, HWh);
    prep_ht<<<BN, 256, 0, stream>>>(H, HhT);
    prep_w1<<<16, 256, 0, stream>>>(W1, W1q);
    prep_wt<<<32, 256, 0, stream>>>(Whh, WTq);
    decoder_scan<<<NBLK, 512, 0, stream>>>(Y, W2, Wih, bih, bhh,
                                           fcW, fcb, fcfW, fcfb,
                                           HWh, HhT, W1q, WTq, out);
}

// Round 4
// 1375.960 us; speedup vs baseline: 2.3515x; 1.7355x over previous
//
#include <hip/hip_runtime.h>
#include <hip/hip_fp16.h>

#define TN 64
#define BN 2048
#define G 4
#define NBLK (BN / G)   // 512 blocks x 512 threads, 2 blocks/CU

typedef _Float16 h2f __attribute__((ext_vector_type(2)));
union U4 {
    uint4 u;
    h2f h[4];
    _Float16 f16[8];
};

// keep loaded values opaque so the compiler cannot re-load them each step
#define LAUNDER4(v) asm volatile("" : "+v"((v).x), "+v"((v).y), "+v"((v).z), "+v"((v).w))

__device__ __forceinline__ float fast_sigmoid(float x) {
    return __builtin_amdgcn_rcpf(1.f + __expf(-x));
}
__device__ __forceinline__ float fast_tanh(float x) {
    return fmaf(2.f, fast_sigmoid(2.f * x), -1.f);
}

// ---- HW[b,t,f] = H[b,t,:] @ W1[256:384,:] + b1, fp16 linear [b*T+t][128]
__global__ __launch_bounds__(256) void prep_hw(
    const float* __restrict__ H, const float* __restrict__ W1,
    const float* __restrict__ b1, __half* __restrict__ HWh) {
    __shared__ float sH[16 * 128];
    const int i = threadIdx.x;
    const long r0 = (long)blockIdx.x * 16;
    #pragma unroll
    for (int u = 0; u < 8; ++u) sH[u * 256 + i] = H[r0 * 128 + u * 256 + i];
    __syncthreads();
    const int f = i & 127;
    const int half_ = i >> 7;
    float acc[8];
    float bb = b1[f];
    #pragma unroll
    for (int u = 0; u < 8; ++u) acc[u] = bb;
    #pragma unroll 4
    for (int h = 0; h < 128; ++h) {
        float wv = W1[(256 + h) * 128 + f];
        #pragma unroll
        for (int u = 0; u < 8; ++u)
            acc[u] = fmaf(sH[(half_ + 2 * u) * 128 + h], wv, acc[u]);
    }
    #pragma unroll
    for (int u = 0; u < 8; ++u)
        HWh[(r0 + half_ + 2 * u) * 128 + f] = __float2half(acc[u]);
}

// ---- HhT[b][f][t] = fp16(H[b][t][f])
__global__ __launch_bounds__(256) void prep_ht(
    const float* __restrict__ H, __half* __restrict__ HhT) {
    __shared__ __half sh[64 * 128];
    const int b = blockIdx.x, i = threadIdx.x;
    #pragma unroll
    for (int u = 0; u < 32; ++u) {
        int idx = u * 256 + i;
        sh[idx] = __float2half(H[(long)b * 8192 + idx]);
    }
    __syncthreads();
    const int f = i >> 1, t0 = (i & 1) * 32;
    __half* ob = HhT + (long)b * 8192 + (long)i * 32;
    #pragma unroll
    for (int k = 0; k < 32; ++k) ob[k] = sh[(t0 + k) * 128 + f];
}

// ---- W1q[u][f] = fp16 of W1[u*8+0..7][f] packed as uint4 (u=0..31)
__global__ __launch_bounds__(256) void prep_w1(
    const float* __restrict__ W1, uint4* __restrict__ W1q) {
    int tid = blockIdx.x * 256 + threadIdx.x;   // 4096
    int u = tid >> 7, f = tid & 127;
    __half tmp[8];
    #pragma unroll
    for (int c = 0; c < 8; ++c) tmp[c] = __float2half(W1[(u * 8 + c) * 128 + f]);
    W1q[tid] = *(const uint4*)tmp;
}

// ---- WTq[k8][n] = fp16 of Whh[n][k8*8+0..7] packed as uint4 (k8=0..15)
__global__ __launch_bounds__(256) void prep_wt(
    const float* __restrict__ Whh, uint4* __restrict__ WTq) {
    int tid = blockIdx.x * 256 + threadIdx.x;   // 8192
    int k8 = tid >> 9, n = tid & 511;
    __half tmp[8];
    #pragma unroll
    for (int c = 0; c < 8; ++c) tmp[c] = __float2half(Whh[n * 128 + k8 * 8 + c]);
    WTq[tid] = *(const uint4*)tmp;
}

// ---- persistent scan: HW in LDS, H & W1 slices in laundered registers
__global__ __launch_bounds__(512, 4) void decoder_scan(
    const float* __restrict__ Y, const float* __restrict__ W2,
    const float* __restrict__ Wih, const float* __restrict__ bih,
    const float* __restrict__ bhh, const float* __restrict__ fcW,
    const float* __restrict__ fcb, const float* __restrict__ fcfW,
    const float* __restrict__ fcfb,
    const __half* __restrict__ HWh, const __half* __restrict__ HhT,
    const uint4* __restrict__ W1q, const uint4* __restrict__ WTq,
    float* __restrict__ out) {

    __shared__ __align__(16) __half sHW[4 * 64 * 128]; // 65536 B, swizzled
    __shared__ __align__(16) float scratch[2048];      // 8192 B (partials/e/gates)
    __shared__ __align__(16) __half sdcH[4 * 256];     // 2048 B [d|c] fp16
    __shared__ __align__(16) float sp[512];            // 2048 B p, then ctx
    __shared__ __align__(16) float sbeta[256];         // 1024 B
    __shared__ __align__(16) float sW2[128];           // 512 B
    __shared__ __align__(16) float sY[256];            // 1024 B
    __shared__ float sy[4];                            // total ~80.4 KB

    const int tid = threadIdx.x;
    const int bbase = blockIdx.x * G;
    const int g_hi = tid >> 7;          // doubles as jc in ph1
    const int f_lo = tid & 127;
    const int lane = tid & 63;
    const int wv = tid >> 6;
    const int g2 = tid >> 7;            // ph2 mapping (g, fc, tt)
    const int fc = (tid >> 6) & 1;
    const int tt = tid & 63;

    // ---- init ----
    // HW tile -> LDS with XOR-16 chunk swizzle (row r chunk c stored at c^(r&15))
    {
        const uint4* src = (const uint4*)(HWh + (long)bbase * (TN * 128));
        #pragma unroll
        for (int u = 0; u < 8; ++u) {
            int idx = u * 512 + tid;          // 16B-chunk index, 0..4095
            int row = idx >> 4, c = idx & 15;
            ((uint4*)sHW)[row * 16 + (c ^ (row & 15))] = src[idx];
        }
    }
    // H[g_hi][0:64][f_lo] slice -> registers (laundered)
    uint4 hr[8];
    {
        const uint4* src = (const uint4*)(HhT + (((long)(bbase + g_hi) * 128 + f_lo) * 64));
        #pragma unroll
        for (int u = 0; u < 8; ++u) { hr[u] = src[u]; LAUNDER4(hr[u]); }
    }
    // W1[jc*64 .. jc*64+63][f_lo] slice -> registers (laundered)
    uint4 w1r[8];
    {
        #pragma unroll
        for (int u = 0; u < 8; ++u) {
            w1r[u] = W1q[(g_hi * 8 + u) * 128 + f_lo];
            LAUNDER4(w1r[u]);
        }
    }
    sdcH[tid] = __float2half(0.f);
    sdcH[tid + 512] = __float2half(0.f);
    if (tid < 128) sW2[tid] = W2[tid];
    if (tid < 256) sY[tid] = Y[(long)bbase * TN + tid];   // [g][t] contiguous
    float c_reg = 0.f;
    const float wih_r = Wih[tid];
    const float bsum_r = bih[tid] + bhh[tid];
    const float fcw0 = fcW[lane], fcw1 = fcW[lane + 64];
    const float fcw2 = fcW[128], fcb0 = fcb[0];
    __syncthreads();

    #pragma unroll 1
    for (int t = 0; t < TN; ++t) {
        // ---- ph1: partial p over j-range [jc*64, jc*64+64), W1 from regs ----
        {
            float pa0 = 0.f, pa1 = 0.f, pa2 = 0.f, pa3 = 0.f;
            #pragma unroll
            for (int u = 0; u < 8; ++u) {
                U4 w; w.u = w1r[u];
                U4 d0; d0.u = *(const uint4*)&sdcH[0 * 256 + g_hi * 64 + u * 8];
                U4 d1; d1.u = *(const uint4*)&sdcH[1 * 256 + g_hi * 64 + u * 8];
                U4 d2; d2.u = *(const uint4*)&sdcH[2 * 256 + g_hi * 64 + u * 8];
                U4 d3; d3.u = *(const uint4*)&sdcH[3 * 256 + g_hi * 64 + u * 8];
                #pragma unroll
                for (int q = 0; q < 4; ++q) {
                    pa0 = __builtin_amdgcn_fdot2(d0.h[q], w.h[q], pa0, false);
                    pa1 = __builtin_amdgcn_fdot2(d1.h[q], w.h[q], pa1, false);
                    pa2 = __builtin_amdgcn_fdot2(d2.h[q], w.h[q], pa2, false);
                    pa3 = __builtin_amdgcn_fdot2(d3.h[q], w.h[q], pa3, false);
                }
            }
            scratch[g_hi * 512 + 0 * 128 + f_lo] = pa0;
            scratch[g_hi * 512 + 1 * 128 + f_lo] = pa1;
            scratch[g_hi * 512 + 2 * 128 + f_lo] = pa2;
            scratch[g_hi * 512 + 3 * 128 + f_lo] = pa3;
        }
        __syncthreads();
        // ---- ph1r: p[g][f] = sum over jc ----
        sp[tid] = scratch[tid] + scratch[512 + tid]
                + scratch[1024 + tid] + scratch[1536 + tid];
        __syncthreads();

        // ---- ph2: e partials; HW from LDS (swizzled), p/W2 broadcast ----
        {
            const int rowc = (g2 * 64 + tt) * 16;
            const int sw = tt & 15;
            const float* pb = &sp[g2 * 128 + fc * 64];
            const float* w2b = &sW2[fc * 64];
            float eacc = 0.f;
            #pragma unroll
            for (int u = 0; u < 8; ++u) {
                int c = fc * 8 + u;
                U4 hw; hw.u = ((const uint4*)sHW)[rowc + (c ^ sw)];
                float4 p0 = *(const float4*)&pb[u * 8];
                float4 p1 = *(const float4*)&pb[u * 8 + 4];
                float4 q0 = *(const float4*)&w2b[u * 8];
                float4 q1 = *(const float4*)&w2b[u * 8 + 4];
                eacc = fmaf(fast_tanh((float)hw.f16[0] + p0.x), q0.x, eacc);
                eacc = fmaf(fast_tanh((float)hw.f16[1] + p0.y), q0.y, eacc);
                eacc = fmaf(fast_tanh((float)hw.f16[2] + p0.z), q0.z, eacc);
                eacc = fmaf(fast_tanh((float)hw.f16[3] + p0.w), q0.w, eacc);
                eacc = fmaf(fast_tanh((float)hw.f16[4] + p1.x), q1.x, eacc);
                eacc = fmaf(fast_tanh((float)hw.f16[5] + p1.y), q1.y, eacc);
                eacc = fmaf(fast_tanh((float)hw.f16[6] + p1.z), q1.z, eacc);
                eacc = fmaf(fast_tanh((float)hw.f16[7] + p1.w), q1.w, eacc);
            }
            scratch[g2 * 128 + fc * 64 + tt] = eacc;
        }
        __syncthreads();

        // ---- ph3: softmax over T (waves 0-3) ----
        if (wv < 4) {
            float e = scratch[wv * 128 + lane] + scratch[wv * 128 + 64 + lane];
            float m = e;
            #pragma unroll
            for (int d = 1; d < 64; d <<= 1) m = fmaxf(m, __shfl_xor(m, d, 64));
            float ex = __expf(e - m);
            float s = ex;
            #pragma unroll
            for (int d = 1; d < 64; d <<= 1) s += __shfl_xor(s, d, 64);
            sbeta[wv * 64 + lane] = ex * __builtin_amdgcn_rcpf(s);
        }
        __syncthreads();

        // ---- ph4: ctx[g][f] = sum_t beta * H  (H from registers) ----
        {
            const float* bb = &sbeta[g_hi * 64];
            float acc = 0.f;
            #pragma unroll
            for (int u = 0; u < 8; ++u) {
                U4 hh; hh.u = hr[u];
                float4 b0 = *(const float4*)&bb[u * 8];
                float4 b1 = *(const float4*)&bb[u * 8 + 4];
                acc = fmaf((float)hh.f16[0], b0.x, acc);
                acc = fmaf((float)hh.f16[1], b0.y, acc);
                acc = fmaf((float)hh.f16[2], b0.z, acc);
                acc = fmaf((float)hh.f16[3], b0.w, acc);
                acc = fmaf((float)hh.f16[4], b1.x, acc);
                acc = fmaf((float)hh.f16[5], b1.y, acc);
                acc = fmaf((float)hh.f16[6], b1.z, acc);
                acc = fmaf((float)hh.f16[7], b1.w, acc);
            }
            sp[tid] = acc;   // p fully consumed in ph2; sp now holds ctx
        }
        __syncthreads();

        // ---- ph5: y_tilde[g] (waves 0-3) ----
        if (wv < 4) {
            float part = sp[wv * 128 + lane] * fcw0 + sp[wv * 128 + 64 + lane] * fcw1;
            #pragma unroll
            for (int d = 1; d < 64; d <<= 1) part += __shfl_xor(part, d, 64);
            if (lane == 0)
                sy[wv] = fmaf(sY[wv * 64 + t], fcw2, part + fcb0);
        }
        __syncthreads();

        // ---- ph6: gates[g][n] = y~*Wih + d.WTcol_n + bsum (n = tid) ----
        {
            float a0 = fmaf(sy[0], wih_r, bsum_r);
            float a1 = fmaf(sy[1], wih_r, bsum_r);
            float a2 = fmaf(sy[2], wih_r, bsum_r);
            float a3 = fmaf(sy[3], wih_r, bsum_r);
            const uint4* wcol = WTq + tid;
            #pragma unroll 4
            for (int k8 = 0; k8 < 16; ++k8) {
                U4 w; w.u = wcol[k8 * 512];
                U4 d0; d0.u = *(const uint4*)&sdcH[0 * 256 + k8 * 8];
                U4 d1; d1.u = *(const uint4*)&sdcH[1 * 256 + k8 * 8];
                U4 d2; d2.u = *(const uint4*)&sdcH[2 * 256 + k8 * 8];
                U4 d3; d3.u = *(const uint4*)&sdcH[3 * 256 + k8 * 8];
                #pragma unroll
                for (int q = 0; q < 4; ++q) {
                    a0 = __builtin_amdgcn_fdot2(d0.h[q], w.h[q], a0, false);
                    a1 = __builtin_amdgcn_fdot2(d1.h[q], w.h[q], a1, false);
                    a2 = __builtin_amdgcn_fdot2(d2.h[q], w.h[q], a2, false);
                    a3 = __builtin_amdgcn_fdot2(d3.h[q], w.h[q], a3, false);
                }
            }
            scratch[0 * 512 + tid] = a0;
            scratch[1 * 512 + tid] = a1;
            scratch[2 * 512 + tid] = a2;
            scratch[3 * 512 + tid] = a3;
        }
        __syncthreads();

        // ---- ph7: LSTM cell (c in register), write d,c fp16 ----
        {
            float ig = fast_sigmoid(scratch[g_hi * 512 + f_lo]);
            float fg = fast_sigmoid(scratch[g_hi * 512 + 128 + f_lo]);
            float gt = fast_tanh(scratch[g_hi * 512 + 256 + f_lo]);
            float og = fast_sigmoid(scratch[g_hi * 512 + 384 + f_lo]);
            c_reg = fmaf(fg, c_reg, ig * gt);
            float dn = og * fast_tanh(c_reg);
            sdcH[g_hi * 256 + f_lo] = __float2half(dn);
            sdcH[g_hi * 256 + 128 + f_lo] = __float2half(c_reg);
        }
        __syncthreads();
    }

    // ---- epilogue: y_pred = [d, ctx] @ fcfW + fcfb (waves 0-3) ----
    if (wv < 4) {
        const int g = wv;
        float part = __half2float(sdcH[g * 256 + lane]) * fcfW[lane]
                   + __half2float(sdcH[g * 256 + 64 + lane]) * fcfW[64 + lane]
                   + sp[g * 128 + lane] * fcfW[128 + lane]
                   + sp[g * 128 + 64 + lane] * fcfW[192 + lane];
        #pragma unroll
        for (int d = 1; d < 64; d <<= 1) part += __shfl_xor(part, d, 64);
        if (lane == 0) out[bbase + g] = part + fcfb[0];
    }
}

extern "C" void kernel_launch(void* const* d_in, const int* in_sizes, int n_in,
                              void* d_out, int out_size, void* d_ws, size_t ws_size,
                              hipStream_t stream) {
    const float* H    = (const float*)d_in[0];
    const float* Y    = (const float*)d_in[1];
    const float* W1   = (const float*)d_in[2];
    const float* b1   = (const float*)d_in[3];
    const float* W2   = (const float*)d_in[4];
    // d_in[5] = attn_b2: softmax-shift-invariant, unused
    const float* Wih  = (const float*)d_in[6];
    const float* Whh  = (const float*)d_in[7];
    const float* bih  = (const float*)d_in[8];
    const float* bhh  = (const float*)d_in[9];
    const float* fcW  = (const float*)d_in[10];
    const float* fcb  = (const float*)d_in[11];
    const float* fcfW = (const float*)d_in[12];
    const float* fcfb = (const float*)d_in[13];

    char* ws = (char*)d_ws;
    __half* HWh = (__half*)ws;                           // 32 MB
    __half* HhT = (__half*)(ws + 33554432);              // 32 MB
    uint4*  W1q = (uint4*)(ws + 2 * 33554432);           // 64 KB
    uint4*  WTq = (uint4*)(ws + 2 * 33554432 + 65536);   // 128 KB
    float* out = (float*)d_out;

    prep_hw<<<BN * TN / 16, 256, 0, stream>>>(H, W1, b1, HWh);
    prep_ht<<<BN, 256, 0, stream>>>(H, HhT);
    prep_w1<<<16, 256, 0, stream>>>(W1, W1q);
    prep_wt<<<32, 256, 0, stream>>>(Whh, WTq);
    decoder_scan<<<NBLK, 512, 0, stream>>>(Y, W2, Wih, bih, bhh,
                                           fcW, fcb, fcfW, fcfb,
                                           HWh, HhT, W1q, WTq, out);
}

// Round 6
// 1365.798 us; speedup vs baseline: 2.3690x; 1.0074x over previous
//
#include <hip/hip_runtime.h>
#include <hip/hip_fp16.h>

#define TN 64
#define BN 2048
#define G 4
#define NBLK (BN / G)   // 512 blocks x 512 threads, 2 blocks/CU

typedef _Float16 h2v __attribute__((ext_vector_type(2)));
typedef _Float16 half8 __attribute__((ext_vector_type(8)));
typedef float float4v __attribute__((ext_vector_type(4)));

union FU {
    uint4 u;
    half8 h8;
    h2v hv[4];
    __half2 h2[4];
    _Float16 f16[8];
};
union H2U { __half2 h; h2v v; };

#define LAUNDER4(v) asm volatile("" : "+v"((v).x), "+v"((v).y), "+v"((v).z), "+v"((v).w))

__device__ __forceinline__ float fast_sigmoid(float x) {
    return __builtin_amdgcn_rcpf(1.f + __expf(-x));
}
__device__ __forceinline__ float fast_tanhf(float x) {
    return fmaf(2.f, fast_sigmoid(2.f * x), -1.f);
}
__device__ __forceinline__ float fdot2f(__half2 a, __half2 b, float c) {
    H2U ua; ua.h = a; H2U ub; ub.h = b;
    return __builtin_amdgcn_fdot2(ua.v, ub.v, c, false);
}
// packed fp16 tanh: t=2^(k*x)=e^{-2x}; r=1/(1+t)=sigmoid(2x); tanh=2r-1
__device__ __forceinline__ __half2 tanh2(__half2 x, __half2 kk, __half2 one2,
                                         __half2 two2, __half2 none2) {
    __half2 tv = h2exp2(__hmul2(x, kk));
    __half2 r = h2rcp(__hadd2(tv, one2));
    return __hfma2(two2, r, none2);
}

// dc swizzled offset (halves). e in [0,256): [d|c]. chunk c of row g at slot
// (c&16)|((c&15)^g) so MFMA A-frag b128 reads are spread across banks.
__device__ __forceinline__ int dc_off(int g, int e) {
    int c = e >> 3;
    int slot = (c & 16) | ((c & 15) ^ (g & 15));
    return g * 256 + slot * 8 + (e & 7);
}

// ---- HW[b,t,f] = H[b,t,:] @ W1[256:384,:] + b1, fp16 linear [b*T+t][128]
__global__ __launch_bounds__(256) void prep_hw(
    const float* __restrict__ H, const float* __restrict__ W1,
    const float* __restrict__ b1, __half* __restrict__ HWh) {
    __shared__ float sH[16 * 128];
    const int i = threadIdx.x;
    const long r0 = (long)blockIdx.x * 16;
    #pragma unroll
    for (int u = 0; u < 8; ++u) sH[u * 256 + i] = H[r0 * 128 + u * 256 + i];
    __syncthreads();
    const int f = i & 127;
    const int half_ = i >> 7;
    float acc[8];
    float bb = b1[f];
    #pragma unroll
    for (int u = 0; u < 8; ++u) acc[u] = bb;
    #pragma unroll 4
    for (int h = 0; h < 128; ++h) {
        float wv = W1[(256 + h) * 128 + f];
        #pragma unroll
        for (int u = 0; u < 8; ++u)
            acc[u] = fmaf(sH[(half_ + 2 * u) * 128 + h], wv, acc[u]);
    }
    #pragma unroll
    for (int u = 0; u < 8; ++u)
        HWh[(r0 + half_ + 2 * u) * 128 + f] = __float2half(acc[u]);
}

// ---- HhT[b][f][t] = fp16(H[b][t][f])
__global__ __launch_bounds__(256) void prep_ht(
    const float* __restrict__ H, __half* __restrict__ HhT) {
    __shared__ __half sh[64 * 128];
    const int b = blockIdx.x, i = threadIdx.x;
    #pragma unroll
    for (int u = 0; u < 32; ++u) {
        int idx = u * 256 + i;
        sh[idx] = __float2half(H[(long)b * 8192 + idx]);
    }
    __syncthreads();
    const int f = i >> 1, t0 = (i & 1) * 32;
    __half* ob = HhT + (long)b * 8192 + (long)i * 32;
    #pragma unroll
    for (int k = 0; k < 32; ++k) ob[k] = sh[(t0 + k) * 128 + f];
}

// ---- W1m: W1[0:256][:] in MFMA B-frag layout.
// frag fi = w*8+kt (w=N-tile, kt=K-tile); element j of lane l:
// B[k = kt*32+(l>>4)*8+j][n = w*16+(l&15)]
__global__ __launch_bounds__(256) void prep_w1m(
    const float* __restrict__ W1, __half* __restrict__ W1m) {
    int tid = blockIdx.x * 256 + threadIdx.x;   // 32768
    int fi = tid >> 9, rem = tid & 511, l = rem >> 3, j = rem & 7;
    int w = fi >> 3, kt = fi & 7;
    int row = kt * 32 + (l >> 4) * 8 + j;       // k in dc
    int col = w * 16 + (l & 15);                // f
    W1m[tid] = __float2half(W1[row * 128 + col]);
}

// ---- WTm: Whh^T in MFMA B-frag layout. frag fi = nt*4+kt:
// B[k = kt*32+(l>>4)*8+j][n = nt*16+(l&15)] = Whh[n][k]
__global__ __launch_bounds__(256) void prep_wtm(
    const float* __restrict__ Whh, __half* __restrict__ WTm) {
    int tid = blockIdx.x * 256 + threadIdx.x;   // 65536
    int fi = tid >> 9, rem = tid & 511, l = rem >> 3, j = rem & 7;
    int nt = fi >> 2, kt = fi & 3;
    int k = kt * 32 + (l >> 4) * 8 + j;
    int n = nt * 16 + (l & 15);
    WTm[tid] = __float2half(Whh[n * 128 + k]);
}

struct SMem {
    __half hw[4 * 64 * 128];   // 65536 B, XOR-16 chunk swizzled
    __half dc[4 * 256];        // 2048 B, dc_off swizzle
    float sg[2048];            // 8192 B gates [g][512]
    float se[512];             // 2048 B e-values
    float sp[512];             // 2048 B p, then ctx [g][128]
    __half beta[256];          // 512 B fp16 beta [g][64]
    __half w2h[128];           // 256 B
    float sY[256];             // 1024 B
    float hs[8];               // 32 B wave partial sums for y~
};                             // total 81696 B <= 81920 -> 2 blocks/CU

__global__ __launch_bounds__(512, 4) void decoder_scan(
    const float* __restrict__ Y, const float* __restrict__ W2,
    const float* __restrict__ Wih, const float* __restrict__ bih,
    const float* __restrict__ bhh, const float* __restrict__ fcW,
    const float* __restrict__ fcb, const float* __restrict__ fcfW,
    const float* __restrict__ fcfb,
    const __half* __restrict__ HWh, const __half* __restrict__ HhT,
    const uint4* __restrict__ W1m4, const uint4* __restrict__ WTm4,
    float* __restrict__ out) {

    __shared__ SMem sm;

    const int tid = threadIdx.x;
    const int bbase = blockIdx.x * G;
    const int g_hi = tid >> 7;
    const int f_lo = tid & 127;
    const int lane = tid & 63;
    const int wv = tid >> 6;            // wave 0..7
    const int g2 = tid >> 7;            // ph2 mapping
    const int fc = (tid >> 6) & 1;
    const int tt = tid & 63;

    // ---- init ----
    // HW tile -> LDS, XOR-16 chunk swizzle (row r chunk c at c^(r&15))
    {
        const uint4* src = (const uint4*)(HWh + (long)bbase * (TN * 128));
        #pragma unroll
        for (int u = 0; u < 8; ++u) {
            int idx = u * 512 + tid;
            int row = idx >> 4, c = idx & 15;
            ((uint4*)sm.hw)[row * 16 + (c ^ (row & 15))] = src[idx];
        }
    }
    // H[g][0:64][f] slice -> laundered registers
    uint4 hr[8];
    {
        const uint4* src = (const uint4*)(HhT + (((long)(bbase + g_hi) * 128 + f_lo) * 64));
        #pragma unroll
        for (int u = 0; u < 8; ++u) { hr[u] = src[u]; LAUNDER4(hr[u]); }
    }
    // W1 B-frags for this wave -> laundered registers (8 frags = 32 VGPR)
    uint4 w1f[8];
    {
        #pragma unroll
        for (int kt = 0; kt < 8; ++kt) {
            w1f[kt] = W1m4[(size_t)(wv * 8 + kt) * 64 + lane];
            LAUNDER4(w1f[kt]);
        }
    }
    ((unsigned*)sm.dc)[tid] = 0u;                  // zero d,c
    if (tid < 128) sm.w2h[tid] = __float2half(W2[tid]);
    if (tid < 256) sm.sY[tid] = Y[(long)bbase * TN + tid];
    float c_reg = 0.f;
    float wih4[4], bs4[4];
    #pragma unroll
    for (int q = 0; q < 4; ++q) {
        wih4[q] = Wih[q * 128 + f_lo];
        bs4[q] = bih[q * 128 + f_lo] + bhh[q * 128 + f_lo];
    }
    const float fcwf = fcW[f_lo];
    const float fcw2 = fcW[128], fcb0 = fcb[0];
    __syncthreads();

    #pragma unroll 1
    for (int t = 0; t < TN; ++t) {
        // ==== region A: p = dc@W1 (MFMA) + gates = d@WhhT (MFMA) ====
        {
            // A-fragments from swizzled dc (rows >=4 read harmless garbage)
            FU afr[8];
            const int m = lane & 15, q = lane >> 4;
            #pragma unroll
            for (int kt = 0; kt < 8; ++kt) {
                int c = kt * 4 + q;
                int slot = (c & 16) | ((c & 15) ^ m);
                afr[kt].u = *(const uint4*)&sm.dc[m * 256 + slot * 8];
            }
            // gates: 4 N-tiles x 4 K-tiles, B from global (L2-hot)
            const uint4* wtg = WTm4 + (size_t)(wv * 16) * 64 + lane;
            float4v gacc[4];
            #pragma unroll
            for (int i = 0; i < 4; ++i) {
                gacc[i] = (float4v){0.f, 0.f, 0.f, 0.f};
                #pragma unroll
                for (int kt = 0; kt < 4; ++kt) {
                    FU b; b.u = wtg[(i * 4 + kt) * 64];
                    gacc[i] = __builtin_amdgcn_mfma_f32_16x16x32_f16(
                        afr[kt].h8, b.h8, gacc[i], 0, 0, 0);
                }
            }
            // p: 8 K-tiles, B = W1 frags in registers
            float4v pacc = (float4v){0.f, 0.f, 0.f, 0.f};
            #pragma unroll
            for (int kt = 0; kt < 8; ++kt) {
                FU b; b.u = w1f[kt];
                pacc = __builtin_amdgcn_mfma_f32_16x16x32_f16(
                    afr[kt].h8, b.h8, pacc, 0, 0, 0);
            }
            // D rows 0-3 live in lanes 0-15, reg r = g
            if (lane < 16) {
                #pragma unroll
                for (int r = 0; r < 4; ++r) {
                    sm.sp[r * 128 + wv * 16 + lane] = pacc[r];
                    #pragma unroll
                    for (int i = 0; i < 4; ++i)
                        sm.sg[r * 512 + (wv * 4 + i) * 16 + lane] = gacc[i][r];
                }
            }
        }
        __syncthreads();

        // ==== ph2: e partials, packed fp16 tanh ====
        {
            const int rowc = (g2 * 64 + tt) * 16, sw = tt & 15, cb = fc * 8;
            const uint4* hwb = (const uint4*)sm.hw;
            const float* pb = &sm.sp[g2 * 128 + fc * 64];
            const __half2* w2b = (const __half2*)&sm.w2h[fc * 64];
            const __half2 kk = __float2half2_rn(-2.88539008f);
            const __half2 one2 = __float2half2_rn(1.f);
            const __half2 two2 = __float2half2_rn(2.f);
            const __half2 none2 = __float2half2_rn(-1.f);
            float eacc = 0.f;
            #pragma unroll
            for (int u = 0; u < 8; ++u) {
                FU hw; hw.u = hwb[rowc + ((cb + u) ^ sw)];
                float4 p0 = *(const float4*)&pb[u * 8];
                float4 p1 = *(const float4*)&pb[u * 8 + 4];
                __half2 pa = __floats2half2_rn(p0.x, p0.y);
                __half2 pb2 = __floats2half2_rn(p0.z, p0.w);
                __half2 pc = __floats2half2_rn(p1.x, p1.y);
                __half2 pd = __floats2half2_rn(p1.z, p1.w);
                __half2 th0 = tanh2(__hadd2(hw.h2[0], pa), kk, one2, two2, none2);
                __half2 th1 = tanh2(__hadd2(hw.h2[1], pb2), kk, one2, two2, none2);
                __half2 th2 = tanh2(__hadd2(hw.h2[2], pc), kk, one2, two2, none2);
                __half2 th3 = tanh2(__hadd2(hw.h2[3], pd), kk, one2, two2, none2);
                eacc = fdot2f(th0, w2b[u * 4 + 0], eacc);
                eacc = fdot2f(th1, w2b[u * 4 + 1], eacc);
                eacc = fdot2f(th2, w2b[u * 4 + 2], eacc);
                eacc = fdot2f(th3, w2b[u * 4 + 3], eacc);
            }
            sm.se[g2 * 128 + fc * 64 + tt] = eacc;
        }
        __syncthreads();

        // ==== ph3: softmax over T (waves 0-3), beta -> fp16 ====
        if (wv < 4) {
            float e = sm.se[wv * 128 + lane] + sm.se[wv * 128 + 64 + lane];
            float m = e;
            #pragma unroll
            for (int d = 1; d < 64; d <<= 1) m = fmaxf(m, __shfl_xor(m, d, 64));
            float ex = __expf(e - m);
            float s = ex;
            #pragma unroll
            for (int d = 1; d < 64; d <<= 1) s += __shfl_xor(s, d, 64);
            sm.beta[wv * 64 + lane] = __float2half(ex * __builtin_amdgcn_rcpf(s));
        }
        __syncthreads();

        // ==== ph4: ctx via fdot2 (H in regs, beta fp16) + fused y~ reduce ====
        {
            const uint4* bb = (const uint4*)&sm.beta[g_hi * 64];
            float cacc = 0.f;
            #pragma unroll
            for (int u = 0; u < 8; ++u) {
                FU hh; hh.u = hr[u];
                FU bt; bt.u = bb[u];
                #pragma unroll
                for (int q = 0; q < 4; ++q)
                    cacc = fdot2f(hh.h2[q], bt.h2[q], cacc);
            }
            sm.sp[tid] = cacc;   // ctx (sp's p fully consumed in ph2)
            float v = cacc * fcwf;
            #pragma unroll
            for (int d = 1; d < 64; d <<= 1) v += __shfl_xor(v, d, 64);
            if (lane == 0) sm.hs[wv] = v;
        }
        __syncthreads();

        // ==== ph7: LSTM cell; sy computed inline from hs ====
        {
            float syg = sm.hs[2 * g_hi] + sm.hs[2 * g_hi + 1]
                      + fmaf(sm.sY[g_hi * 64 + t], fcw2, fcb0);
            float a0 = sm.sg[g_hi * 512 + f_lo]       + fmaf(syg, wih4[0], bs4[0]);
            float a1 = sm.sg[g_hi * 512 + 128 + f_lo] + fmaf(syg, wih4[1], bs4[1]);
            float a2 = sm.sg[g_hi * 512 + 256 + f_lo] + fmaf(syg, wih4[2], bs4[2]);
            float a3 = sm.sg[g_hi * 512 + 384 + f_lo] + fmaf(syg, wih4[3], bs4[3]);
            float ig = fast_sigmoid(a0);
            float fg = fast_sigmoid(a1);
            float gt = fast_tanhf(a2);
            float og = fast_sigmoid(a3);
            c_reg = fmaf(fg, c_reg, ig * gt);
            float dn = og * fast_tanhf(c_reg);
            sm.dc[dc_off(g_hi, f_lo)] = __float2half(dn);
            sm.dc[dc_off(g_hi, 128 + f_lo)] = __float2half(c_reg);
        }
        __syncthreads();
    }

    // ---- epilogue ----
    if (wv < 4) {
        const int g = wv;
        float part = __half2float(sm.dc[dc_off(g, lane)]) * fcfW[lane]
                   + __half2float(sm.dc[dc_off(g, 64 + lane)]) * fcfW[64 + lane]
                   + sm.sp[g * 128 + lane] * fcfW[128 + lane]
                   + sm.sp[g * 128 + 64 + lane] * fcfW[192 + lane];
        #pragma unroll
        for (int d = 1; d < 64; d <<= 1) part += __shfl_xor(part, d, 64);
        if (lane == 0) out[bbase + g] = part + fcfb[0];
    }
}

extern "C" void kernel_launch(void* const* d_in, const int* in_sizes, int n_in,
                              void* d_out, int out_size, void* d_ws, size_t ws_size,
                              hipStream_t stream) {
    const float* H    = (const float*)d_in[0];
    const float* Y    = (const float*)d_in[1];
    const float* W1   = (const float*)d_in[2];
    const float* b1   = (const float*)d_in[3];
    const float* W2   = (const float*)d_in[4];
    // d_in[5] = attn_b2: softmax-shift-invariant, unused
    const float* Wih  = (const float*)d_in[6];
    const float* Whh  = (const float*)d_in[7];
    const float* bih  = (const float*)d_in[8];
    const float* bhh  = (const float*)d_in[9];
    const float* fcW  = (const float*)d_in[10];
    const float* fcb  = (const float*)d_in[11];
    const float* fcfW = (const float*)d_in[12];
    const float* fcfb = (const float*)d_in[13];

    char* ws = (char*)d_ws;
    __half* HWh = (__half*)ws;                            // 32 MB
    __half* HhT = (__half*)(ws + 33554432);               // 32 MB
    __half* W1m = (__half*)(ws + 2 * 33554432);           // 64 KB
    __half* WTm = (__half*)(ws + 2 * 33554432 + 65536);   // 128 KB
    float* out = (float*)d_out;

    prep_hw<<<BN * TN / 16, 256, 0, stream>>>(H, W1, b1, HWh);
    prep_ht<<<BN, 256, 0, stream>>>(H, HhT);
    prep_w1m<<<128, 256, 0, stream>>>(W1, W1m);
    prep_wtm<<<256, 256, 0, stream>>>(Whh, WTm);
    decoder_scan<<<NBLK, 512, 0, stream>>>(Y, W2, Wih, bih, bhh,
                                           fcW, fcb, fcfW, fcfb,
                                           HWh, HhT, (const uint4*)W1m,
                                           (const uint4*)WTm, out);
}

// Round 7
// 1339.897 us; speedup vs baseline: 2.4148x; 1.0193x over previous
//
#include <hip/hip_runtime.h>
#include <hip/hip_fp16.h>

#define TN 64
#define BN 2048
#define G 4
#define NBLK (BN / G)   // 512 blocks x 512 threads, 2 blocks/CU

typedef _Float16 h2v __attribute__((ext_vector_type(2)));
typedef _Float16 half8 __attribute__((ext_vector_type(8)));
typedef float float4v __attribute__((ext_vector_type(4)));

union FU {
    uint4 u;
    half8 h8;
    h2v hv[4];
    __half2 h2[4];
    _Float16 f16[8];
};
union H2U { __half2 h; h2v v; };

#define LAUNDER4(v) asm volatile("" : "+v"((v).x), "+v"((v).y), "+v"((v).z), "+v"((v).w))

__device__ __forceinline__ float fast_sigmoid(float x) {
    return __builtin_amdgcn_rcpf(1.f + __expf(-x));
}
__device__ __forceinline__ float fast_tanhf(float x) {
    return fmaf(2.f, fast_sigmoid(2.f * x), -1.f);
}
__device__ __forceinline__ float fdot2f(__half2 a, __half2 b, float c) {
    H2U ua; ua.h = a; H2U ub; ub.h = b;
    return __builtin_amdgcn_fdot2(ua.v, ub.v, c, false);
}
// packed fp16 tanh: t=2^(k*x)=e^{-2x}; r=1/(1+t)=sigmoid(2x); tanh=2r-1
__device__ __forceinline__ __half2 tanh2(__half2 x, __half2 kk, __half2 one2,
                                         __half2 two2, __half2 none2) {
    __half2 tv = h2exp2(__hmul2(x, kk));
    __half2 r = h2rcp(__hadd2(tv, one2));
    return __hfma2(two2, r, none2);
}

// dc swizzled offset (halves). e in [0,256): [d|c]. chunk c of row g at slot
// (c&16)|((c&15)^g) so MFMA A-frag b128 reads are spread across banks.
__device__ __forceinline__ int dc_off(int g, int e) {
    int c = e >> 3;
    int slot = (c & 16) | ((c & 15) ^ (g & 15));
    return g * 256 + slot * 8 + (e & 7);
}

// ---- HW[b,t,f] = H[b,t,:] @ W1[256:384,:] + b1, fp16 linear [b*T+t][128]
__global__ __launch_bounds__(256) void prep_hw(
    const float* __restrict__ H, const float* __restrict__ W1,
    const float* __restrict__ b1, __half* __restrict__ HWh) {
    __shared__ float sH[16 * 128];
    const int i = threadIdx.x;
    const long r0 = (long)blockIdx.x * 16;
    #pragma unroll
    for (int u = 0; u < 8; ++u) sH[u * 256 + i] = H[r0 * 128 + u * 256 + i];
    __syncthreads();
    const int f = i & 127;
    const int half_ = i >> 7;
    float acc[8];
    float bb = b1[f];
    #pragma unroll
    for (int u = 0; u < 8; ++u) acc[u] = bb;
    #pragma unroll 4
    for (int h = 0; h < 128; ++h) {
        float wv = W1[(256 + h) * 128 + f];
        #pragma unroll
        for (int u = 0; u < 8; ++u)
            acc[u] = fmaf(sH[(half_ + 2 * u) * 128 + h], wv, acc[u]);
    }
    #pragma unroll
    for (int u = 0; u < 8; ++u)
        HWh[(r0 + half_ + 2 * u) * 128 + f] = __float2half(acc[u]);
}

// ---- HhT[b][f][t] = fp16(H[b][t][f])
__global__ __launch_bounds__(256) void prep_ht(
    const float* __restrict__ H, __half* __restrict__ HhT) {
    __shared__ __half sh[64 * 128];
    const int b = blockIdx.x, i = threadIdx.x;
    #pragma unroll
    for (int u = 0; u < 32; ++u) {
        int idx = u * 256 + i;
        sh[idx] = __float2half(H[(long)b * 8192 + idx]);
    }
    __syncthreads();
    const int f = i >> 1, t0 = (i & 1) * 32;
    __half* ob = HhT + (long)b * 8192 + (long)i * 32;
    #pragma unroll
    for (int k = 0; k < 32; ++k) ob[k] = sh[(t0 + k) * 128 + f];
}

// ---- W1m: W1[0:256][:] in MFMA B-frag layout.
// frag fi = w*8+kt (w=N-tile, kt=K-tile); element j of lane l:
// B[k = kt*32+(l>>4)*8+j][n = w*16+(l&15)]
__global__ __launch_bounds__(256) void prep_w1m(
    const float* __restrict__ W1, __half* __restrict__ W1m) {
    int tid = blockIdx.x * 256 + threadIdx.x;   // 32768
    int fi = tid >> 9, rem = tid & 511, l = rem >> 3, j = rem & 7;
    int w = fi >> 3, kt = fi & 7;
    int row = kt * 32 + (l >> 4) * 8 + j;       // k in dc
    int col = w * 16 + (l & 15);                // f
    W1m[tid] = __float2half(W1[row * 128 + col]);
}

// ---- WTm: Whh^T in MFMA B-frag layout. frag fi = nt*4+kt:
// B[k = kt*32+(l>>4)*8+j][n = nt*16+(l&15)] = Whh[n][k]
__global__ __launch_bounds__(256) void prep_wtm(
    const float* __restrict__ Whh, __half* __restrict__ WTm) {
    int tid = blockIdx.x * 256 + threadIdx.x;   // 65536
    int fi = tid >> 9, rem = tid & 511, l = rem >> 3, j = rem & 7;
    int nt = fi >> 2, kt = fi & 3;
    int k = kt * 32 + (l >> 4) * 8 + j;
    int n = nt * 16 + (l & 15);
    WTm[tid] = __float2half(Whh[n * 128 + k]);
}

struct SMem {
    __half hw[4 * 64 * 128];   // 65536 B, XOR-16 chunk swizzled
    __half dc[4 * 256];        // 2048 B, dc_off swizzle
    float sg[2048];            // 8192 B gates [g][512]
    float se[512];             // 2048 B e-values
    float sp[512];             // 2048 B p, then ctx [g][128]
    __half beta[256];          // 512 B fp16 beta [g][64]
    __half w2h[128];           // 256 B
    float sY[256];             // 1024 B
    float hs[8];               // 32 B wave partial sums for y~
};                             // total 81696 B <= 81920 -> 2 blocks/CU

__global__ __launch_bounds__(512, 4) void decoder_scan(
    const float* __restrict__ Y, const float* __restrict__ W2,
    const float* __restrict__ Wih, const float* __restrict__ bih,
    const float* __restrict__ bhh, const float* __restrict__ fcW,
    const float* __restrict__ fcb, const float* __restrict__ fcfW,
    const float* __restrict__ fcfb,
    const __half* __restrict__ HWh, const __half* __restrict__ HhT,
    const uint4* __restrict__ W1m4, const uint4* __restrict__ WTm4,
    float* __restrict__ out) {

    __shared__ SMem sm;

    const int tid = threadIdx.x;
    const int bbase = blockIdx.x * G;
    const int g_hi = tid >> 7;
    const int f_lo = tid & 127;
    const int lane = tid & 63;
    const int wv = tid >> 6;            // wave 0..7
    const int g2 = tid >> 7;            // ph2 mapping
    const int fc = (tid >> 6) & 1;
    const int tt = tid & 63;

    // ---- init ----
    // HW tile -> LDS, XOR-16 chunk swizzle (row r chunk c at c^(r&15))
    {
        const uint4* src = (const uint4*)(HWh + (long)bbase * (TN * 128));
        #pragma unroll
        for (int u = 0; u < 8; ++u) {
            int idx = u * 512 + tid;
            int row = idx >> 4, c = idx & 15;
            ((uint4*)sm.hw)[row * 16 + (c ^ (row & 15))] = src[idx];
        }
    }
    // H[g][0:64][f] slice -> laundered registers (32 VGPR)
    uint4 hr[8];
    {
        const uint4* src = (const uint4*)(HhT + (((long)(bbase + g_hi) * 128 + f_lo) * 64));
        #pragma unroll
        for (int u = 0; u < 8; ++u) { hr[u] = src[u]; LAUNDER4(hr[u]); }
    }
    ((unsigned*)sm.dc)[tid] = 0u;                  // zero d,c
    if (tid < 128) sm.w2h[tid] = __float2half(W2[tid]);
    if (tid < 256) sm.sY[tid] = Y[(long)bbase * TN + tid];
    float c_reg = 0.f;
    float wih4[4], bs4[4];
    #pragma unroll
    for (int q = 0; q < 4; ++q) {
        wih4[q] = Wih[q * 128 + f_lo];
        bs4[q] = bih[q * 128 + f_lo] + bhh[q * 128 + f_lo];
    }
    const float fcwf = fcW[f_lo];
    const float fcw2 = fcW[128], fcb0 = fcb[0];
    __syncthreads();

    #pragma unroll 1
    for (int t = 0; t < TN; ++t) {
        // ==== region A: p = dc@W1 (MFMA) + gates = d@WhhT (MFMA) ====
        // Both B-operands streamed from global (192 KB/XCD hot set, L2-resident)
        {
            // A-fragments from swizzled dc
            FU afr[8];
            const int m = lane & 15, q = lane >> 4;
            #pragma unroll
            for (int kt = 0; kt < 8; ++kt) {
                int c = kt * 4 + q;
                int slot = (c & 16) | ((c & 15) ^ m);
                afr[kt].u = *(const uint4*)&sm.dc[m * 256 + slot * 8];
            }
            // p: 8 K-tiles, B streamed from W1m
            {
                const uint4* w1g = W1m4 + (size_t)(wv * 8) * 64 + lane;
                float4v pacc = (float4v){0.f, 0.f, 0.f, 0.f};
                #pragma unroll
                for (int kt = 0; kt < 8; ++kt) {
                    FU b; b.u = w1g[kt * 64];
                    pacc = __builtin_amdgcn_mfma_f32_16x16x32_f16(
                        afr[kt].h8, b.h8, pacc, 0, 0, 0);
                }
                if (lane < 16) {
                    #pragma unroll
                    for (int r = 0; r < 4; ++r)
                        sm.sp[r * 128 + wv * 16 + lane] = pacc[r];
                }
            }
            // gates: 4 N-tiles x 4 K-tiles, B streamed from WTm; store per tile
            {
                const uint4* wtg = WTm4 + (size_t)(wv * 16) * 64 + lane;
                #pragma unroll
                for (int i = 0; i < 4; ++i) {
                    float4v gacc = (float4v){0.f, 0.f, 0.f, 0.f};
                    #pragma unroll
                    for (int kt = 0; kt < 4; ++kt) {
                        FU b; b.u = wtg[(i * 4 + kt) * 64];
                        gacc = __builtin_amdgcn_mfma_f32_16x16x32_f16(
                            afr[kt].h8, b.h8, gacc, 0, 0, 0);
                    }
                    if (lane < 16) {
                        #pragma unroll
                        for (int r = 0; r < 4; ++r)
                            sm.sg[r * 512 + (wv * 4 + i) * 16 + lane] = gacc[r];
                    }
                }
            }
        }
        __syncthreads();

        // ==== ph2: e partials, packed fp16 tanh ====
        {
            const int rowc = (g2 * 64 + tt) * 16, sw = tt & 15, cb = fc * 8;
            const uint4* hwb = (const uint4*)sm.hw;
            const float* pb = &sm.sp[g2 * 128 + fc * 64];
            const __half2* w2b = (const __half2*)&sm.w2h[fc * 64];
            const __half2 kk = __float2half2_rn(-2.88539008f);
            const __half2 one2 = __float2half2_rn(1.f);
            const __half2 two2 = __float2half2_rn(2.f);
            const __half2 none2 = __float2half2_rn(-1.f);
            float eacc = 0.f;
            #pragma unroll
            for (int u = 0; u < 8; ++u) {
                FU hw; hw.u = hwb[rowc + ((cb + u) ^ sw)];
                float4 p0 = *(const float4*)&pb[u * 8];
                float4 p1 = *(const float4*)&pb[u * 8 + 4];
                __half2 pa = __floats2half2_rn(p0.x, p0.y);
                __half2 pb2 = __floats2half2_rn(p0.z, p0.w);
                __half2 pc = __floats2half2_rn(p1.x, p1.y);
                __half2 pd = __floats2half2_rn(p1.z, p1.w);
                __half2 th0 = tanh2(__hadd2(hw.h2[0], pa), kk, one2, two2, none2);
                __half2 th1 = tanh2(__hadd2(hw.h2[1], pb2), kk, one2, two2, none2);
                __half2 th2 = tanh2(__hadd2(hw.h2[2], pc), kk, one2, two2, none2);
                __half2 th3 = tanh2(__hadd2(hw.h2[3], pd), kk, one2, two2, none2);
                eacc = fdot2f(th0, w2b[u * 4 + 0], eacc);
                eacc = fdot2f(th1, w2b[u * 4 + 1], eacc);
                eacc = fdot2f(th2, w2b[u * 4 + 2], eacc);
                eacc = fdot2f(th3, w2b[u * 4 + 3], eacc);
            }
            sm.se[g2 * 128 + fc * 64 + tt] = eacc;
        }
        __syncthreads();

        // ==== ph3: softmax over T (waves 0-3), beta -> fp16 ====
        if (wv < 4) {
            float e = sm.se[wv * 128 + lane] + sm.se[wv * 128 + 64 + lane];
            float m = e;
            #pragma unroll
            for (int d = 1; d < 64; d <<= 1) m = fmaxf(m, __shfl_xor(m, d, 64));
            float ex = __expf(e - m);
            float s = ex;
            #pragma unroll
            for (int d = 1; d < 64; d <<= 1) s += __shfl_xor(s, d, 64);
            sm.beta[wv * 64 + lane] = __float2half(ex * __builtin_amdgcn_rcpf(s));
        }
        __syncthreads();

        // ==== ph4: ctx via fdot2 (H in regs, beta fp16) + fused y~ reduce ====
        {
            const uint4* bb = (const uint4*)&sm.beta[g_hi * 64];
            float cacc = 0.f;
            #pragma unroll
            for (int u = 0; u < 8; ++u) {
                FU hh; hh.u = hr[u];
                FU bt; bt.u = bb[u];
                #pragma unroll
                for (int q = 0; q < 4; ++q)
                    cacc = fdot2f(hh.h2[q], bt.h2[q], cacc);
            }
            sm.sp[tid] = cacc;   // ctx (sp's p fully consumed in ph2)
            float v = cacc * fcwf;
            #pragma unroll
            for (int d = 1; d < 64; d <<= 1) v += __shfl_xor(v, d, 64);
            if (lane == 0) sm.hs[wv] = v;
        }
        __syncthreads();

        // ==== ph7: LSTM cell; sy computed inline from hs ====
        {
            float syg = sm.hs[2 * g_hi] + sm.hs[2 * g_hi + 1]
                      + fmaf(sm.sY[g_hi * 64 + t], fcw2, fcb0);
            float a0 = sm.sg[g_hi * 512 + f_lo]       + fmaf(syg, wih4[0], bs4[0]);
            float a1 = sm.sg[g_hi * 512 + 128 + f_lo] + fmaf(syg, wih4[1], bs4[1]);
            float a2 = sm.sg[g_hi * 512 + 256 + f_lo] + fmaf(syg, wih4[2], bs4[2]);
            float a3 = sm.sg[g_hi * 512 + 384 + f_lo] + fmaf(syg, wih4[3], bs4[3]);
            float ig = fast_sigmoid(a0);
            float fg = fast_sigmoid(a1);
            float gt = fast_tanhf(a2);
            float og = fast_sigmoid(a3);
            c_reg = fmaf(fg, c_reg, ig * gt);
            float dn = og * fast_tanhf(c_reg);
            sm.dc[dc_off(g_hi, f_lo)] = __float2half(dn);
            sm.dc[dc_off(g_hi, 128 + f_lo)] = __float2half(c_reg);
        }
        __syncthreads();
    }

    // ---- epilogue ----
    if (wv < 4) {
        const int g = wv;
        float part = __half2float(sm.dc[dc_off(g, lane)]) * fcfW[lane]
                   + __half2float(sm.dc[dc_off(g, 64 + lane)]) * fcfW[64 + lane]
                   + sm.sp[g * 128 + lane] * fcfW[128 + lane]
                   + sm.sp[g * 128 + 64 + lane] * fcfW[192 + lane];
        #pragma unroll
        for (int d = 1; d < 64; d <<= 1) part += __shfl_xor(part, d, 64);
        if (lane == 0) out[bbase + g] = part + fcfb[0];
    }
}

extern "C" void kernel_launch(void* const* d_in, const int* in_sizes, int n_in,
                              void* d_out, int out_size, void* d_ws, size_t ws_size,
                              hipStream_t stream) {
    const float* H    = (const float*)d_in[0];
    const float* Y    = (const float*)d_in[1];
    const float* W1   = (const float*)d_in[2];
    const float* b1   = (const float*)d_in[3];
    const float* W2   = (const float*)d_in[4];
    // d_in[5] = attn_b2: softmax-shift-invariant, unused
    const float* Wih  = (const float*)d_in[6];
    const float* Whh  = (const float*)d_in[7];
    const float* bih  = (const float*)d_in[8];
    const float* bhh  = (const float*)d_in[9];
    const float* fcW  = (const float*)d_in[10];
    const float* fcb  = (const float*)d_in[11];
    const float* fcfW = (const float*)d_in[12];
    const float* fcfb = (const float*)d_in[13];

    char* ws = (char*)d_ws;
    __half* HWh = (__half*)ws;                            // 32 MB
    __half* HhT = (__half*)(ws + 33554432);               // 32 MB
    __half* W1m = (__half*)(ws + 2 * 33554432);           // 64 KB
    __half* WTm = (__half*)(ws + 2 * 33554432 + 65536);   // 128 KB
    float* out = (float*)d_out;

    prep_hw<<<BN * TN / 16, 256, 0, stream>>>(H, W1, b1, HWh);
    prep_ht<<<BN, 256, 0, stream>>>(H, HhT);
    prep_w1m<<<128, 256, 0, stream>>>(W1, W1m);
    prep_wtm<<<256, 256, 0, stream>>>(Whh, WTm);
    decoder_scan<<<NBLK, 512, 0, stream>>>(Y, W2, Wih, bih, bhh,
                                           fcW, fcb, fcfW, fcfb,
                                           HWh, HhT, (const uint4*)W1m,
                                           (const uint4*)WTm, out);
}

// Round 8
// 813.510 us; speedup vs baseline: 3.9774x; 1.6471x over previous
//
#include <hip/hip_runtime.h>
#include <hip/hip_fp16.h>

#define TN 64
#define BN 2048
#define G 4
#define NBLK (BN / G)   // 512 blocks x 512 threads, 1 block/CU (VGPR-bound)

typedef _Float16 h2v __attribute__((ext_vector_type(2)));
typedef _Float16 half8 __attribute__((ext_vector_type(8)));
typedef float float4v __attribute__((ext_vector_type(4)));

union FU {
    uint4 u;
    half8 h8;
    h2v hv[4];
    __half2 h2[4];
    _Float16 f16[8];
};
union H2U { __half2 h; h2v v; };

#define LAUNDER4(v) asm volatile("" : "+v"((v).x), "+v"((v).y), "+v"((v).z), "+v"((v).w))

__device__ __forceinline__ float fast_sigmoid(float x) {
    return __builtin_amdgcn_rcpf(1.f + __expf(-x));
}
__device__ __forceinline__ float fast_tanhf(float x) {
    return fmaf(2.f, fast_sigmoid(2.f * x), -1.f);
}
__device__ __forceinline__ float fdot2f(__half2 a, __half2 b, float c) {
    H2U ua; ua.h = a; H2U ub; ub.h = b;
    return __builtin_amdgcn_fdot2(ua.v, ub.v, c, false);
}
// packed fp16 tanh: t=2^(k*x)=e^{-2x}; r=1/(1+t)=sigmoid(2x); tanh=2r-1
__device__ __forceinline__ __half2 tanh2(__half2 x, __half2 kk, __half2 one2,
                                         __half2 two2, __half2 none2) {
    __half2 tv = h2exp2(__hmul2(x, kk));
    __half2 r = h2rcp(__hadd2(tv, one2));
    return __hfma2(two2, r, none2);
}

// dc swizzled offset (halves). e in [0,256): [d|c]. chunk c of row g at slot
// (c&16)|((c&15)^g) so MFMA A-frag b128 reads are spread across banks.
__device__ __forceinline__ int dc_off(int g, int e) {
    int c = e >> 3;
    int slot = (c & 16) | ((c & 15) ^ (g & 15));
    return g * 256 + slot * 8 + (e & 7);
}

// ---- HW[b,t,f] = H[b,t,:] @ W1[256:384,:] + b1, fp16 linear [b*T+t][128]
__global__ __launch_bounds__(256) void prep_hw(
    const float* __restrict__ H, const float* __restrict__ W1,
    const float* __restrict__ b1, __half* __restrict__ HWh) {
    __shared__ float sH[16 * 128];
    const int i = threadIdx.x;
    const long r0 = (long)blockIdx.x * 16;
    #pragma unroll
    for (int u = 0; u < 8; ++u) sH[u * 256 + i] = H[r0 * 128 + u * 256 + i];
    __syncthreads();
    const int f = i & 127;
    const int half_ = i >> 7;
    float acc[8];
    float bb = b1[f];
    #pragma unroll
    for (int u = 0; u < 8; ++u) acc[u] = bb;
    #pragma unroll 4
    for (int h = 0; h < 128; ++h) {
        float wv = W1[(256 + h) * 128 + f];
        #pragma unroll
        for (int u = 0; u < 8; ++u)
            acc[u] = fmaf(sH[(half_ + 2 * u) * 128 + h], wv, acc[u]);
    }
    #pragma unroll
    for (int u = 0; u < 8; ++u)
        HWh[(r0 + half_ + 2 * u) * 128 + f] = __float2half(acc[u]);
}

// ---- HhT[b][f][t] = fp16(H[b][t][f])
__global__ __launch_bounds__(256) void prep_ht(
    const float* __restrict__ H, __half* __restrict__ HhT) {
    __shared__ __half sh[64 * 128];
    const int b = blockIdx.x, i = threadIdx.x;
    #pragma unroll
    for (int u = 0; u < 32; ++u) {
        int idx = u * 256 + i;
        sh[idx] = __float2half(H[(long)b * 8192 + idx]);
    }
    __syncthreads();
    const int f = i >> 1, t0 = (i & 1) * 32;
    __half* ob = HhT + (long)b * 8192 + (long)i * 32;
    #pragma unroll
    for (int k = 0; k < 32; ++k) ob[k] = sh[(t0 + k) * 128 + f];
}

// ---- W1m: W1[0:256][:] in MFMA B-frag layout.
// frag fi = w*8+kt (w=N-tile, kt=K-tile); element j of lane l:
// B[k = kt*32+(l>>4)*8+j][n = w*16+(l&15)]
__global__ __launch_bounds__(256) void prep_w1m(
    const float* __restrict__ W1, __half* __restrict__ W1m) {
    int tid = blockIdx.x * 256 + threadIdx.x;   // 32768
    int fi = tid >> 9, rem = tid & 511, l = rem >> 3, j = rem & 7;
    int w = fi >> 3, kt = fi & 7;
    int row = kt * 32 + (l >> 4) * 8 + j;       // k in dc
    int col = w * 16 + (l & 15);                // f
    W1m[tid] = __float2half(W1[row * 128 + col]);
}

// ---- WTm: Whh^T in MFMA B-frag layout. frag fi = nt*4+kt:
// B[k = kt*32+(l>>4)*8+j][n = nt*16+(l&15)] = Whh[n][k]
__global__ __launch_bounds__(256) void prep_wtm(
    const float* __restrict__ Whh, __half* __restrict__ WTm) {
    int tid = blockIdx.x * 256 + threadIdx.x;   // 65536
    int fi = tid >> 9, rem = tid & 511, l = rem >> 3, j = rem & 7;
    int nt = fi >> 2, kt = fi & 3;
    int k = kt * 32 + (l >> 4) * 8 + j;
    int n = nt * 16 + (l & 15);
    WTm[tid] = __float2half(Whh[n * 128 + k]);
}

struct SMem {
    __half dc[4 * 256];        // 2048 B, dc_off swizzle
    float sg[2048];            // 8192 B gates [g][512]
    float se[512];             // 2048 B e-values
    float sp[512];             // 2048 B p, then ctx [g][128]
    __half beta[256];          // 512 B fp16 beta [g][64]
    __half w2h[128];           // 256 B
    float sY[256];             // 1024 B
    float hs[8];               // 32 B wave partial sums for y~
};                             // ~16.2 KB -> occupancy VGPR-bound

// 2 waves/SIMD floor -> 256-VGPR budget; all time-invariant slices in regs
__global__ __launch_bounds__(512, 2) void decoder_scan(
    const float* __restrict__ Y, const float* __restrict__ W2,
    const float* __restrict__ Wih, const float* __restrict__ bih,
    const float* __restrict__ bhh, const float* __restrict__ fcW,
    const float* __restrict__ fcb, const float* __restrict__ fcfW,
    const float* __restrict__ fcfb,
    const __half* __restrict__ HWh, const __half* __restrict__ HhT,
    const uint4* __restrict__ W1m4, const uint4* __restrict__ WTm4,
    float* __restrict__ out) {

    __shared__ SMem sm;

    const int tid = threadIdx.x;
    const int bbase = blockIdx.x * G;
    const int g_hi = tid >> 7;
    const int f_lo = tid & 127;
    const int lane = tid & 63;
    const int wv = tid >> 6;            // wave 0..7
    const int g2 = tid >> 7;            // ph2 mapping
    const int fc = (tid >> 6) & 1;
    const int tt = tid & 63;

    // ---- init: all four time-invariant slices -> laundered registers ----
    // HW[g2][tt][fc*64 .. +64] (ph2 operand), 32 VGPR
    uint4 hwr[8];
    {
        const uint4* src = (const uint4*)(HWh + (((long)(bbase + g2) * 64 + tt) * 128 + fc * 64));
        #pragma unroll
        for (int u = 0; u < 8; ++u) { hwr[u] = src[u]; LAUNDER4(hwr[u]); }
    }
    // H[g][0:64][f] (ph4 operand), 32 VGPR
    uint4 hr[8];
    {
        const uint4* src = (const uint4*)(HhT + (((long)(bbase + g_hi) * 128 + f_lo) * 64));
        #pragma unroll
        for (int u = 0; u < 8; ++u) { hr[u] = src[u]; LAUNDER4(hr[u]); }
    }
    // W1 B-frags (8 = 32 VGPR), WhhT B-frags (16 = 64 VGPR)
    uint4 w1f[8];
    #pragma unroll
    for (int kt = 0; kt < 8; ++kt) {
        w1f[kt] = W1m4[(size_t)(wv * 8 + kt) * 64 + lane];
        LAUNDER4(w1f[kt]);
    }
    uint4 wtf[16];
    #pragma unroll
    for (int q = 0; q < 16; ++q) {
        wtf[q] = WTm4[(size_t)(wv * 16 + q) * 64 + lane];
        LAUNDER4(wtf[q]);
    }
    ((unsigned*)sm.dc)[tid] = 0u;                  // zero d,c
    if (tid < 128) sm.w2h[tid] = __float2half(W2[tid]);
    if (tid < 256) sm.sY[tid] = Y[(long)bbase * TN + tid];
    float c_reg = 0.f;
    float wih4[4], bs4[4];
    #pragma unroll
    for (int q = 0; q < 4; ++q) {
        wih4[q] = Wih[q * 128 + f_lo];
        bs4[q] = bih[q * 128 + f_lo] + bhh[q * 128 + f_lo];
    }
    const float fcwf = fcW[f_lo];
    const float fcw2 = fcW[128], fcb0 = fcb[0];
    __syncthreads();

    #pragma unroll 1
    for (int t = 0; t < TN; ++t) {
        // ==== region A: p = dc@W1 (MFMA) + gates = d@WhhT (MFMA), B in regs ====
        {
            // A-fragments from swizzled dc
            FU afr[8];
            const int m = lane & 15, q = lane >> 4;
            #pragma unroll
            for (int kt = 0; kt < 8; ++kt) {
                int c = kt * 4 + q;
                int slot = (c & 16) | ((c & 15) ^ m);
                afr[kt].u = *(const uint4*)&sm.dc[m * 256 + slot * 8];
            }
            // p: 8 K-tiles
            {
                float4v pacc = (float4v){0.f, 0.f, 0.f, 0.f};
                #pragma unroll
                for (int kt = 0; kt < 8; ++kt) {
                    FU b; b.u = w1f[kt];
                    pacc = __builtin_amdgcn_mfma_f32_16x16x32_f16(
                        afr[kt].h8, b.h8, pacc, 0, 0, 0);
                }
                if (lane < 16) {
                    #pragma unroll
                    for (int r = 0; r < 4; ++r)
                        sm.sp[r * 128 + wv * 16 + lane] = pacc[r];
                }
            }
            // gates: 4 N-tiles x 4 K-tiles (d half of dc only)
            #pragma unroll
            for (int i = 0; i < 4; ++i) {
                float4v gacc = (float4v){0.f, 0.f, 0.f, 0.f};
                #pragma unroll
                for (int kt = 0; kt < 4; ++kt) {
                    FU b; b.u = wtf[i * 4 + kt];
                    gacc = __builtin_amdgcn_mfma_f32_16x16x32_f16(
                        afr[kt].h8, b.h8, gacc, 0, 0, 0);
                }
                if (lane < 16) {
                    #pragma unroll
                    for (int r = 0; r < 4; ++r)
                        sm.sg[r * 512 + (wv * 4 + i) * 16 + lane] = gacc[r];
                }
            }
        }
        __syncthreads();

        // ==== ph2: e partials, packed fp16 tanh, HW from registers ====
        {
            const float* pb = &sm.sp[g2 * 128 + fc * 64];
            const __half2* w2b = (const __half2*)&sm.w2h[fc * 64];
            const __half2 kk = __float2half2_rn(-2.88539008f);
            const __half2 one2 = __float2half2_rn(1.f);
            const __half2 two2 = __float2half2_rn(2.f);
            const __half2 none2 = __float2half2_rn(-1.f);
            float eacc = 0.f;
            #pragma unroll
            for (int u = 0; u < 8; ++u) {
                FU hw; hw.u = hwr[u];
                float4 p0 = *(const float4*)&pb[u * 8];
                float4 p1 = *(const float4*)&pb[u * 8 + 4];
                __half2 pa = __floats2half2_rn(p0.x, p0.y);
                __half2 pb2 = __floats2half2_rn(p0.z, p0.w);
                __half2 pc = __floats2half2_rn(p1.x, p1.y);
                __half2 pd = __floats2half2_rn(p1.z, p1.w);
                __half2 th0 = tanh2(__hadd2(hw.h2[0], pa), kk, one2, two2, none2);
                __half2 th1 = tanh2(__hadd2(hw.h2[1], pb2), kk, one2, two2, none2);
                __half2 th2 = tanh2(__hadd2(hw.h2[2], pc), kk, one2, two2, none2);
                __half2 th3 = tanh2(__hadd2(hw.h2[3], pd), kk, one2, two2, none2);
                eacc = fdot2f(th0, w2b[u * 4 + 0], eacc);
                eacc = fdot2f(th1, w2b[u * 4 + 1], eacc);
                eacc = fdot2f(th2, w2b[u * 4 + 2], eacc);
                eacc = fdot2f(th3, w2b[u * 4 + 3], eacc);
            }
            sm.se[g2 * 128 + fc * 64 + tt] = eacc;
        }
        __syncthreads();

        // ==== ph3: softmax over T (waves 0-3), beta -> fp16 ====
        if (wv < 4) {
            float e = sm.se[wv * 128 + lane] + sm.se[wv * 128 + 64 + lane];
            float m = e;
            #pragma unroll
            for (int d = 1; d < 64; d <<= 1) m = fmaxf(m, __shfl_xor(m, d, 64));
            float ex = __expf(e - m);
            float s = ex;
            #pragma unroll
            for (int d = 1; d < 64; d <<= 1) s += __shfl_xor(s, d, 64);
            sm.beta[wv * 64 + lane] = __float2half(ex * __builtin_amdgcn_rcpf(s));
        }
        __syncthreads();

        // ==== ph4: ctx via fdot2 (H in regs, beta fp16) + fused y~ reduce ====
        {
            const uint4* bb = (const uint4*)&sm.beta[g_hi * 64];
            float cacc = 0.f;
            #pragma unroll
            for (int u = 0; u < 8; ++u) {
                FU hh; hh.u = hr[u];
                FU bt; bt.u = bb[u];
                #pragma unroll
                for (int q = 0; q < 4; ++q)
                    cacc = fdot2f(hh.h2[q], bt.h2[q], cacc);
            }
            sm.sp[tid] = cacc;   // ctx (sp's p fully consumed in ph2)
            float v = cacc * fcwf;
            #pragma unroll
            for (int d = 1; d < 64; d <<= 1) v += __shfl_xor(v, d, 64);
            if (lane == 0) sm.hs[wv] = v;
        }
        __syncthreads();

        // ==== ph7: LSTM cell; sy computed inline from hs ====
        {
            float syg = sm.hs[2 * g_hi] + sm.hs[2 * g_hi + 1]
                      + fmaf(sm.sY[g_hi * 64 + t], fcw2, fcb0);
            float a0 = sm.sg[g_hi * 512 + f_lo]       + fmaf(syg, wih4[0], bs4[0]);
            float a1 = sm.sg[g_hi * 512 + 128 + f_lo] + fmaf(syg, wih4[1], bs4[1]);
            float a2 = sm.sg[g_hi * 512 + 256 + f_lo] + fmaf(syg, wih4[2], bs4[2]);
            float a3 = sm.sg[g_hi * 512 + 384 + f_lo] + fmaf(syg, wih4[3], bs4[3]);
            float ig = fast_sigmoid(a0);
            float fg = fast_sigmoid(a1);
            float gt = fast_tanhf(a2);
            float og = fast_sigmoid(a3);
            c_reg = fmaf(fg, c_reg, ig * gt);
            float dn = og * fast_tanhf(c_reg);
            sm.dc[dc_off(g_hi, f_lo)] = __float2half(dn);
            sm.dc[dc_off(g_hi, 128 + f_lo)] = __float2half(c_reg);
        }
        __syncthreads();
    }

    // ---- epilogue ----
    if (wv < 4) {
        const int g = wv;
        float part = __half2float(sm.dc[dc_off(g, lane)]) * fcfW[lane]
                   + __half2float(sm.dc[dc_off(g, 64 + lane)]) * fcfW[64 + lane]
                   + sm.sp[g * 128 + lane] * fcfW[128 + lane]
                   + sm.sp[g * 128 + 64 + lane] * fcfW[192 + lane];
        #pragma unroll
        for (int d = 1; d < 64; d <<= 1) part += __shfl_xor(part, d, 64);
        if (lane == 0) out[bbase + g] = part + fcfb[0];
    }
}

extern "C" void kernel_launch(void* const* d_in, const int* in_sizes, int n_in,
                              void* d_out, int out_size, void* d_ws, size_t ws_size,
                              hipStream_t stream) {
    const float* H    = (const float*)d_in[0];
    const float* Y    = (const float*)d_in[1];
    const float* W1   = (const float*)d_in[2];
    const float* b1   = (const float*)d_in[3];
    const float* W2   = (const float*)d_in[4];
    // d_in[5] = attn_b2: softmax-shift-invariant, unused
    const float* Wih  = (const float*)d_in[6];
    const float* Whh  = (const float*)d_in[7];
    const float* bih  = (const float*)d_in[8];
    const float* bhh  = (const float*)d_in[9];
    const float* fcW  = (const float*)d_in[10];
    const float* fcb  = (const float*)d_in[11];
    const float* fcfW = (const float*)d_in[12];
    const float* fcfb = (const float*)d_in[13];

    char* ws = (char*)d_ws;
    __half* HWh = (__half*)ws;                            // 32 MB
    __half* HhT = (__half*)(ws + 33554432);               // 32 MB
    __half* W1m = (__half*)(ws + 2 * 33554432);           // 64 KB
    __half* WTm = (__half*)(ws + 2 * 33554432 + 65536);   // 128 KB
    float* out = (float*)d_out;

    prep_hw<<<BN * TN / 16, 256, 0, stream>>>(H, W1, b1, HWh);
    prep_ht<<<BN, 256, 0, stream>>>(H, HhT);
    prep_w1m<<<128, 256, 0, stream>>>(W1, W1m);
    prep_wtm<<<256, 256, 0, stream>>>(Whh, WTm);
    decoder_scan<<<NBLK, 512, 0, stream>>>(Y, W2, Wih, bih, bhh,
                                           fcW, fcb, fcfW, fcfb,
                                           HWh, HhT, (const uint4*)W1m,
                                           (const uint4*)WTm, out);
}

// Round 9
// 773.742 us; speedup vs baseline: 4.1818x; 1.0514x over previous
//
#include <hip/hip_runtime.h>
#include <hip/hip_fp16.h>

#define TN 64
#define BN 2048
#define G 4
#define NBLK (BN / G)   // 512 blocks x 512 threads, 1 block/CU (VGPR-bound)

typedef _Float16 h2v __attribute__((ext_vector_type(2)));
typedef _Float16 half8 __attribute__((ext_vector_type(8)));
typedef float float4v __attribute__((ext_vector_type(4)));

union FU {
    uint4 u;
    half8 h8;
    h2v hv[4];
    __half2 h2[4];
    _Float16 f16[8];
};
union H2U { __half2 h; h2v v; };

#define LAUNDER4(v) asm volatile("" : "+v"((v).x), "+v"((v).y), "+v"((v).z), "+v"((v).w))

__device__ __forceinline__ float fast_sigmoid(float x) {
    return __builtin_amdgcn_rcpf(1.f + __expf(-x));
}
__device__ __forceinline__ float fast_tanhf(float x) {
    return fmaf(2.f, fast_sigmoid(2.f * x), -1.f);
}
__device__ __forceinline__ float fdot2f(__half2 a, __half2 b, float c) {
    H2U ua; ua.h = a; H2U ub; ub.h = b;
    return __builtin_amdgcn_fdot2(ua.v, ub.v, c, false);
}
// packed fp16 tanh: t=2^(k*x)=e^{-2x}; r=1/(1+t)=sigmoid(2x); tanh=2r-1
__device__ __forceinline__ __half2 tanh2(__half2 x, __half2 kk, __half2 one2,
                                         __half2 two2, __half2 none2) {
    __half2 tv = h2exp2(__hmul2(x, kk));
    __half2 r = h2rcp(__hadd2(tv, one2));
    return __hfma2(two2, r, none2);
}

// dc swizzled offset (halves): chunk c of row g at slot (c&16)|((c&15)^g)
__device__ __forceinline__ int dc_off(int g, int e) {
    int c = e >> 3;
    int slot = (c & 16) | ((c & 15) ^ (g & 15));
    return g * 256 + slot * 8 + (e & 7);
}

// ---- HW[b,t,f] = H[b,t,:] @ W1[256:384,:] + b1, fp16 linear [b*T+t][128]
__global__ __launch_bounds__(256) void prep_hw(
    const float* __restrict__ H, const float* __restrict__ W1,
    const float* __restrict__ b1, __half* __restrict__ HWh) {
    __shared__ float sH[16 * 128];
    const int i = threadIdx.x;
    const long r0 = (long)blockIdx.x * 16;
    #pragma unroll
    for (int u = 0; u < 8; ++u) sH[u * 256 + i] = H[r0 * 128 + u * 256 + i];
    __syncthreads();
    const int f = i & 127;
    const int half_ = i >> 7;
    float acc[8];
    float bb = b1[f];
    #pragma unroll
    for (int u = 0; u < 8; ++u) acc[u] = bb;
    #pragma unroll 4
    for (int h = 0; h < 128; ++h) {
        float wv = W1[(256 + h) * 128 + f];
        #pragma unroll
        for (int u = 0; u < 8; ++u)
            acc[u] = fmaf(sH[(half_ + 2 * u) * 128 + h], wv, acc[u]);
    }
    #pragma unroll
    for (int u = 0; u < 8; ++u)
        HWh[(r0 + half_ + 2 * u) * 128 + f] = __float2half(acc[u]);
}

// ---- HhT[b][f][t] = fp16(H[b][t][f])
__global__ __launch_bounds__(256) void prep_ht(
    const float* __restrict__ H, __half* __restrict__ HhT) {
    __shared__ __half sh[64 * 128];
    const int b = blockIdx.x, i = threadIdx.x;
    #pragma unroll
    for (int u = 0; u < 32; ++u) {
        int idx = u * 256 + i;
        sh[idx] = __float2half(H[(long)b * 8192 + idx]);
    }
    __syncthreads();
    const int f = i >> 1, t0 = (i & 1) * 32;
    __half* ob = HhT + (long)b * 8192 + (long)i * 32;
    #pragma unroll
    for (int k = 0; k < 32; ++k) ob[k] = sh[(t0 + k) * 128 + f];
}

// ---- W1m: W1[0:256][:] in MFMA B-frag layout (frag fi = w*8+kt)
__global__ __launch_bounds__(256) void prep_w1m(
    const float* __restrict__ W1, __half* __restrict__ W1m) {
    int tid = blockIdx.x * 256 + threadIdx.x;   // 32768
    int fi = tid >> 9, rem = tid & 511, l = rem >> 3, j = rem & 7;
    int w = fi >> 3, kt = fi & 7;
    int row = kt * 32 + (l >> 4) * 8 + j;
    int col = w * 16 + (l & 15);
    W1m[tid] = __float2half(W1[row * 128 + col]);
}

// ---- WTm: Whh^T in MFMA B-frag layout (frag fi = nt*4+kt)
__global__ __launch_bounds__(256) void prep_wtm(
    const float* __restrict__ Whh, __half* __restrict__ WTm) {
    int tid = blockIdx.x * 256 + threadIdx.x;   // 65536
    int fi = tid >> 9, rem = tid & 511, l = rem >> 3, j = rem & 7;
    int nt = fi >> 2, kt = fi & 3;
    int k = kt * 32 + (l >> 4) * 8 + j;
    int n = nt * 16 + (l & 15);
    WTm[tid] = __float2half(Whh[n * 128 + k]);
}

struct SMem {
    __half ht[4 * 128 * 64];   // 65536 B H^T tile [g][f][t], granule-XOR swizzle
    __half dc[4 * 256];        // 2048 B, dc_off swizzle
    float sg[2048];            // 8192 B gates [g][512]
    float se[512];             // 2048 B e partials
    __half ctxH[512];          // 1024 B ctx fp16 [g][128] (epilogue)
    __half spH[512];           // 1024 B p fp16 [g][128]
    __half beta[256];          // 512 B fp16 beta [g][64]
    __half w2h[128];           // 256 B
    float sY[256];             // 1024 B
};                             // 81664 B, 1 block/CU

__global__ __launch_bounds__(512, 2) void decoder_scan(
    const float* __restrict__ Y, const float* __restrict__ W2,
    const float* __restrict__ Wih, const float* __restrict__ bih,
    const float* __restrict__ bhh, const float* __restrict__ fcW,
    const float* __restrict__ fcb, const float* __restrict__ fcfW,
    const float* __restrict__ fcfb,
    const __half* __restrict__ HWh, const __half* __restrict__ HhT,
    const uint4* __restrict__ W1m4, const uint4* __restrict__ WTm4,
    float* __restrict__ out) {

    __shared__ SMem sm;

    const int tid = threadIdx.x;
    const int bbase = blockIdx.x * G;
    const int g_hi = tid >> 7;          // == wv>>1
    const int f_lo = tid & 127;
    const int lane = tid & 63;
    const int wv = tid >> 6;            // wave 0..7
    const int g2 = tid >> 7;            // ph2 mapping
    const int fc = (tid >> 6) & 1;
    const int tt = tid & 63;

    // ---- init ----
    // HW[g2][tt][fc*64..+64] slice -> laundered registers (32 VGPR)
    uint4 hwr[8];
    {
        const uint4* src = (const uint4*)(HWh + (((long)(bbase + g2) * 64 + tt) * 128 + fc * 64));
        #pragma unroll
        for (int u = 0; u < 8; ++u) { hwr[u] = src[u]; LAUNDER4(hwr[u]); }
    }
    // H^T tile -> LDS with granule swizzle (granule g of row at g ^ (f&7))
    {
        const uint4* src = (const uint4*)(HhT + (long)bbase * 8192);
        #pragma unroll
        for (int u = 0; u < 8; ++u) {
            int idx = u * 512 + tid;             // granule 0..4095
            int f7 = (idx >> 3) & 7;
            ((uint4*)sm.ht)[(idx & ~7) | ((idx & 7) ^ f7)] = src[idx];
        }
    }
    // W1 B-frags (8 = 32 VGPR), WhhT B-frags (16 = 64 VGPR), laundered
    uint4 w1f[8];
    #pragma unroll
    for (int kt = 0; kt < 8; ++kt) {
        w1f[kt] = W1m4[(size_t)(wv * 8 + kt) * 64 + lane];
        LAUNDER4(w1f[kt]);
    }
    uint4 wtf[16];
    #pragma unroll
    for (int q = 0; q < 16; ++q) {
        wtf[q] = WTm4[(size_t)(wv * 16 + q) * 64 + lane];
        LAUNDER4(wtf[q]);
    }
    ((unsigned*)sm.dc)[tid] = 0u;
    if (tid < 128) sm.w2h[tid] = __float2half(W2[tid]);
    if (tid < 256) sm.sY[tid] = Y[(long)bbase * TN + tid];
    float c_reg = 0.f;
    float wih4[4], bs4[4];
    #pragma unroll
    for (int q = 0; q < 4; ++q) {
        wih4[q] = Wih[q * 128 + f_lo];
        bs4[q] = bih[q * 128 + f_lo] + bhh[q * 128 + f_lo];
    }
    const float fcwa = fcW[f_lo];
    const float fcwb = fcW[f_lo ^ 64];
    const float fcw2 = fcW[128], fcb0 = fcb[0];
    __syncthreads();

    #pragma unroll 1
    for (int t = 0; t < TN; ++t) {
        float4v gacc[4];
        // ==== region A: p + gates MFMAs; gacc held in regs through ph2 ====
        {
            FU afr[8];
            const int m = lane & 15, q = lane >> 4;
            #pragma unroll
            for (int kt = 0; kt < 8; ++kt) {
                int c = kt * 4 + q;
                int slot = (c & 16) | ((c & 15) ^ m);
                afr[kt].u = *(const uint4*)&sm.dc[m * 256 + slot * 8];
            }
            float4v pacc = (float4v){0.f, 0.f, 0.f, 0.f};
            #pragma unroll
            for (int kt = 0; kt < 8; ++kt) {
                FU b; b.u = w1f[kt];
                pacc = __builtin_amdgcn_mfma_f32_16x16x32_f16(
                    afr[kt].h8, b.h8, pacc, 0, 0, 0);
            }
            #pragma unroll
            for (int i = 0; i < 4; ++i) {
                gacc[i] = (float4v){0.f, 0.f, 0.f, 0.f};
                #pragma unroll
                for (int kt = 0; kt < 4; ++kt) {
                    FU b; b.u = wtf[i * 4 + kt];
                    gacc[i] = __builtin_amdgcn_mfma_f32_16x16x32_f16(
                        afr[kt].h8, b.h8, gacc[i], 0, 0, 0);
                }
            }
            // p -> fp16 LDS now; gacc stored after ph2 (MFMA overlaps ph2)
            if (lane < 16) {
                #pragma unroll
                for (int r = 0; r < 4; ++r)
                    sm.spH[r * 128 + wv * 16 + lane] = __float2half(pacc[r]);
            }
        }
        __syncthreads();   // b1

        // ==== ph2: e partials (packed fp16 tanh, p fp16 broadcast) ====
        {
            const uint4* pH = (const uint4*)&sm.spH[g2 * 128 + fc * 64];
            const __half2* w2b = (const __half2*)&sm.w2h[fc * 64];
            const __half2 kk = __float2half2_rn(-2.88539008f);
            const __half2 one2 = __float2half2_rn(1.f);
            const __half2 two2 = __float2half2_rn(2.f);
            const __half2 none2 = __float2half2_rn(-1.f);
            float ea0 = 0.f, ea1 = 0.f, ea2 = 0.f, ea3 = 0.f;
            #pragma unroll
            for (int u = 0; u < 8; ++u) {
                FU hw; hw.u = hwr[u];
                FU pp; pp.u = pH[u];
                __half2 th0 = tanh2(__hadd2(hw.h2[0], pp.h2[0]), kk, one2, two2, none2);
                __half2 th1 = tanh2(__hadd2(hw.h2[1], pp.h2[1]), kk, one2, two2, none2);
                __half2 th2 = tanh2(__hadd2(hw.h2[2], pp.h2[2]), kk, one2, two2, none2);
                __half2 th3 = tanh2(__hadd2(hw.h2[3], pp.h2[3]), kk, one2, two2, none2);
                ea0 = fdot2f(th0, w2b[u * 4 + 0], ea0);
                ea1 = fdot2f(th1, w2b[u * 4 + 1], ea1);
                ea2 = fdot2f(th2, w2b[u * 4 + 2], ea2);
                ea3 = fdot2f(th3, w2b[u * 4 + 3], ea3);
            }
            sm.se[g2 * 128 + fc * 64 + tt] = (ea0 + ea1) + (ea2 + ea3);
            // gate MFMA results -> LDS (issued in region A, completed by now)
            if (lane < 16) {
                #pragma unroll
                for (int i = 0; i < 4; ++i) {
                    #pragma unroll
                    for (int r = 0; r < 4; ++r)
                        sm.sg[r * 512 + (wv * 4 + i) * 16 + lane] = gacc[i][r];
                }
            }
        }
        __syncthreads();   // b2

        // ==== fused ph3+ph4+ph5+ph7: per-wave, barrier-free ====
        {
            // ph3: softmax for this wave's g (redundant across the 2 waves/g)
            float e = sm.se[g_hi * 128 + lane] + sm.se[g_hi * 128 + 64 + lane];
            float ex = __expf(e);   // |e| bounded ~34, fp32 safe, no max pass
            float s = ex;
            #pragma unroll
            for (int d = 1; d < 64; d <<= 1) s += __shfl_xor(s, d, 64);
            sm.beta[g_hi * 64 + lane] = __float2half(ex * __builtin_amdgcn_rcpf(s));
            // ph4: ctx for own f and mirror f^64 (same-wave LDS readback)
            const uint4* bb = (const uint4*)&sm.beta[g_hi * 64];
            const uint4* htb = (const uint4*)sm.ht;
            const int ba = ((g_hi << 7) | f_lo) << 3;
            const int bm = ((g_hi << 7) | (f_lo ^ 64)) << 3;
            const int sw7 = f_lo & 7;
            float ca0 = 0.f, ca1 = 0.f, cb0 = 0.f, cb1 = 0.f;
            #pragma unroll
            for (int u = 0; u < 8; ++u) {
                FU bt; bt.u = bb[u];
                FU h0; h0.u = htb[ba + (u ^ sw7)];
                FU h1; h1.u = htb[bm + (u ^ sw7)];
                ca0 = fdot2f(h0.h2[0], bt.h2[0], ca0);
                ca1 = fdot2f(h0.h2[1], bt.h2[1], ca1);
                ca0 = fdot2f(h0.h2[2], bt.h2[2], ca0);
                ca1 = fdot2f(h0.h2[3], bt.h2[3], ca1);
                cb0 = fdot2f(h1.h2[0], bt.h2[0], cb0);
                cb1 = fdot2f(h1.h2[1], bt.h2[1], cb1);
                cb0 = fdot2f(h1.h2[2], bt.h2[2], cb0);
                cb1 = fdot2f(h1.h2[3], bt.h2[3], cb1);
            }
            float ctx_own = ca0 + ca1;
            float ctx_mir = cb0 + cb1;
            sm.ctxH[g_hi * 128 + f_lo] = __float2half(ctx_own);
            // ph5: y~ via in-wave reduce (covers all 128 f: own + mirror)
            float v = ctx_own * fcwa + ctx_mir * fcwb;
            #pragma unroll
            for (int d = 1; d < 64; d <<= 1) v += __shfl_xor(v, d, 64);
            float syg = v + fmaf(sm.sY[g_hi * 64 + t], fcw2, fcb0);
            // ph7: LSTM cell
            float a0 = sm.sg[g_hi * 512 + f_lo]       + fmaf(syg, wih4[0], bs4[0]);
            float a1 = sm.sg[g_hi * 512 + 128 + f_lo] + fmaf(syg, wih4[1], bs4[1]);
            float a2 = sm.sg[g_hi * 512 + 256 + f_lo] + fmaf(syg, wih4[2], bs4[2]);
            float a3 = sm.sg[g_hi * 512 + 384 + f_lo] + fmaf(syg, wih4[3], bs4[3]);
            float ig = fast_sigmoid(a0);
            float fg = fast_sigmoid(a1);
            float gt = fast_tanhf(a2);
            float og = fast_sigmoid(a3);
            c_reg = fmaf(fg, c_reg, ig * gt);
            float dn = og * fast_tanhf(c_reg);
            sm.dc[dc_off(g_hi, f_lo)] = __float2half(dn);
            sm.dc[dc_off(g_hi, 128 + f_lo)] = __float2half(c_reg);
        }
        __syncthreads();   // b3 (step end)
    }

    // ---- epilogue ----
    if (wv < 4) {
        const int g = wv;
        float part = __half2float(sm.dc[dc_off(g, lane)]) * fcfW[lane]
                   + __half2float(sm.dc[dc_off(g, 64 + lane)]) * fcfW[64 + lane]
                   + __half2float(sm.ctxH[g * 128 + lane]) * fcfW[128 + lane]
                   + __half2float(sm.ctxH[g * 128 + 64 + lane]) * fcfW[192 + lane];
        #pragma unroll
        for (int d = 1; d < 64; d <<= 1) part += __shfl_xor(part, d, 64);
        if (lane == 0) out[bbase + g] = part + fcfb[0];
    }
}

extern "C" void kernel_launch(void* const* d_in, const int* in_sizes, int n_in,
                              void* d_out, int out_size, void* d_ws, size_t ws_size,
                              hipStream_t stream) {
    const float* H    = (const float*)d_in[0];
    const float* Y    = (const float*)d_in[1];
    const float* W1   = (const float*)d_in[2];
    const float* b1   = (const float*)d_in[3];
    const float* W2   = (const float*)d_in[4];
    // d_in[5] = attn_b2: softmax-shift-invariant, unused
    const float* Wih  = (const float*)d_in[6];
    const float* Whh  = (const float*)d_in[7];
    const float* bih  = (const float*)d_in[8];
    const float* bhh  = (const float*)d_in[9];
    const float* fcW  = (const float*)d_in[10];
    const float* fcb  = (const float*)d_in[11];
    const float* fcfW = (const float*)d_in[12];
    const float* fcfb = (const float*)d_in[13];

    char* ws = (char*)d_ws;
    __half* HWh = (__half*)ws;                            // 32 MB
    __half* HhT = (__half*)(ws + 33554432);               // 32 MB
    __half* W1m = (__half*)(ws + 2 * 33554432);           // 64 KB
    __half* WTm = (__half*)(ws + 2 * 33554432 + 65536);   // 128 KB
    float* out = (float*)d_out;

    prep_hw<<<BN * TN / 16, 256, 0, stream>>>(H, W1, b1, HWh);
    prep_ht<<<BN, 256, 0, stream>>>(H, HhT);
    prep_w1m<<<128, 256, 0, stream>>>(W1, W1m);
    prep_wtm<<<256, 256, 0, stream>>>(Whh, WTm);
    decoder_scan<<<NBLK, 512, 0, stream>>>(Y, W2, Wih, bih, bhh,
                                           fcW, fcb, fcfW, fcfb,
                                           HWh, HhT, (const uint4*)W1m,
                                           (const uint4*)WTm, out);
}